// Round 1
// baseline (344.173 us; speedup 1.0000x reference)
//
#include <hip/hip_runtime.h>

// ---------------------------------------------------------------------------
// CausalSelfAttention: qkv GEMM -> causal flash attention -> proj GEMM
// All matmuls via mfma_f32_16x16x32_bf16 (fp32 accum). bf16 tolerance per harness.
//
// ws layout (bytes):
//   x_bf16   [8192][1024]        @ 0          16,777,216
//   wqkvT    [3072][1024]        @ 16777216    6,291,456
//   wprojT   [1024][1024]        @ 23068672    2,097,152
//   q        [128][1024][64]     @ 25165824   16,777,216   (bh, t, d)
//   k        [128][1024][64]     @ 41943040   16,777,216
//   vT       [128][64][1024]     @ 58720256   16,777,216   (bh, d, t)
//   y        [8192][1024]        @ 75497472   16,777,216
// total 92,274,688 bytes
// ---------------------------------------------------------------------------

typedef __bf16 bf16x8 __attribute__((ext_vector_type(8)));
typedef float f32x4 __attribute__((ext_vector_type(4)));
typedef unsigned uint4e __attribute__((ext_vector_type(4)));
typedef unsigned short ushort8e __attribute__((ext_vector_type(8)));

__device__ __forceinline__ unsigned short f2bf(float f) {
  unsigned u = __builtin_bit_cast(unsigned, f);
  u += 0x7fffu + ((u >> 16) & 1u);   // round-to-nearest-even (finite inputs)
  return (unsigned short)(u >> 16);
}

// ---------------- conversion kernels ----------------

__global__ void cvt_x_kernel(const float* __restrict__ in, unsigned short* __restrict__ out) {
  size_t i = (size_t)(blockIdx.x * 256 + threadIdx.x) * 8;
  float4 a = *(const float4*)(in + i);
  float4 b = *(const float4*)(in + i + 4);
  ushort8e o;
  o[0] = f2bf(a.x); o[1] = f2bf(a.y); o[2] = f2bf(a.z); o[3] = f2bf(a.w);
  o[4] = f2bf(b.x); o[5] = f2bf(b.y); o[6] = f2bf(b.z); o[7] = f2bf(b.w);
  *(ushort8e*)(out + i) = o;
}

// w [K][N] fp32 -> wT [N][K] bf16, 32x32 LDS tile transpose
__global__ void cvt_wT_kernel(const float* __restrict__ w, unsigned short* __restrict__ wT,
                              int K, int N) {
  __shared__ float tile[32][33];
  const int n0 = blockIdx.x * 32, k0 = blockIdx.y * 32;
  const int tx = threadIdx.x, ty = threadIdx.y;
#pragma unroll
  for (int i = 0; i < 32; i += 8)
    tile[ty + i][tx] = w[(size_t)(k0 + ty + i) * N + n0 + tx];
  __syncthreads();
#pragma unroll
  for (int i = 0; i < 32; i += 8)
    wT[(size_t)(n0 + ty + i) * K + k0 + tx] = f2bf(tile[tx][ty + i]);
}

// ---------------- GEMM: C[M,N] = A[M,K](bf16) * BT[N,K](bf16)^T + bias ----------------
// EPI 0: scatter to q/k/vT bf16 buffers (qkv GEMM)
// EPI 1: fp32 store to outF (proj GEMM)

#define BM 128
#define BN 128
#define BK 32

template <int EPI>
__global__ __launch_bounds__(256) void gemm_kernel(
    const unsigned short* __restrict__ A, const unsigned short* __restrict__ BT,
    const float* __restrict__ bias, float* __restrict__ outF,
    unsigned short* __restrict__ qO, unsigned short* __restrict__ kO,
    unsigned short* __restrict__ vO, int M, int N, int K) {
  __shared__ __align__(16) unsigned short As[BM * BK];
  __shared__ __align__(16) unsigned short Bs[BN * BK];
  const int tid = threadIdx.x;
  const int w = tid >> 6, lane = tid & 63;
  const int g = lane >> 4, cx = lane & 15;
  const int bm = blockIdx.y * BM, bn = blockIdx.x * BN;
  const int wm = (w >> 1) * 64, wn = (w & 1) * 64;

  // staging: thread t handles 16B chunks (row=t>>2, chunk=t&3) and (+64 rows)
  const int sr = tid >> 2, sc = tid & 3;
  const int swz = (sr >> 1) & 3;  // same for sr and sr+64
  const unsigned short* ga0 = A + (size_t)(bm + sr) * K + sc * 8;
  const unsigned short* ga1 = A + (size_t)(bm + sr + 64) * K + sc * 8;
  const unsigned short* gb0 = BT + (size_t)(bn + sr) * K + sc * 8;
  const unsigned short* gb1 = BT + (size_t)(bn + sr + 64) * K + sc * 8;
  unsigned short* la0 = &As[sr * BK + ((sc ^ swz) << 3)];
  unsigned short* la1 = &As[(sr + 64) * BK + ((sc ^ swz) << 3)];
  unsigned short* lb0 = &Bs[sr * BK + ((sc ^ swz) << 3)];
  unsigned short* lb1 = &Bs[(sr + 64) * BK + ((sc ^ swz) << 3)];

  // fragment read pointers (swizzled chunk = g ^ ((row>>1)&3))
  const unsigned short* ap[4];
  const unsigned short* bp[4];
#pragma unroll
  for (int i = 0; i < 4; ++i) {
    const int R = wm + i * 16 + cx;
    ap[i] = &As[R * BK + ((g ^ ((R >> 1) & 3)) << 3)];
    const int Rb = wn + i * 16 + cx;
    bp[i] = &Bs[Rb * BK + ((g ^ ((Rb >> 1) & 3)) << 3)];
  }

  f32x4 acc[4][4] = {};

  for (int kt = 0; kt < K; kt += BK) {
    uint4 va0 = *(const uint4*)(ga0 + kt);
    uint4 va1 = *(const uint4*)(ga1 + kt);
    uint4 vb0 = *(const uint4*)(gb0 + kt);
    uint4 vb1 = *(const uint4*)(gb1 + kt);
    *(uint4*)la0 = va0;
    *(uint4*)la1 = va1;
    *(uint4*)lb0 = vb0;
    *(uint4*)lb1 = vb1;
    __syncthreads();
    bf16x8 af[4], bfr[4];
#pragma unroll
    for (int i = 0; i < 4; ++i) {
      af[i] = *(const bf16x8*)ap[i];
      bfr[i] = *(const bf16x8*)bp[i];
    }
#pragma unroll
    for (int i = 0; i < 4; ++i)
#pragma unroll
      for (int j = 0; j < 4; ++j)
        acc[i][j] = __builtin_amdgcn_mfma_f32_16x16x32_bf16(af[i], bfr[j], acc[i][j], 0, 0, 0);
    __syncthreads();
  }

  // epilogue: lane holds D[4g+r][cx] per 16x16 block
  if (EPI == 0) {
#pragma unroll
    for (int i = 0; i < 4; ++i) {
      const int m0 = bm + wm + i * 16 + (g << 2);
      const int b = m0 >> 10, t0 = m0 & 1023;
#pragma unroll
      for (int j = 0; j < 4; ++j) {
        const int n = bn + wn + j * 16 + cx;
        const float bv = bias[n];
        const int which = n >> 10, rem = n & 1023;
        const int h = rem >> 6, d = rem & 63;
        const int bh = b * 16 + h;
        if (which == 2) {
          // vT[bh][d][t]: 4 consecutive t -> one 8B store
          uint2 pv;
          pv.x = (unsigned)f2bf(acc[i][j][0] + bv) | ((unsigned)f2bf(acc[i][j][1] + bv) << 16);
          pv.y = (unsigned)f2bf(acc[i][j][2] + bv) | ((unsigned)f2bf(acc[i][j][3] + bv) << 16);
          *(uint2*)(vO + ((size_t)bh * 64 + d) * 1024 + t0) = pv;
        } else {
          unsigned short* dst = (which == 0 ? qO : kO);
#pragma unroll
          for (int r = 0; r < 4; ++r)
            dst[((size_t)bh * 1024 + (t0 + r)) * 64 + d] = f2bf(acc[i][j][r] + bv);
        }
      }
    }
  } else {
#pragma unroll
    for (int i = 0; i < 4; ++i) {
      const int m0 = bm + wm + i * 16 + (g << 2);
#pragma unroll
      for (int j = 0; j < 4; ++j) {
        const int n = bn + wn + j * 16 + cx;
        const float bv = bias[n];
#pragma unroll
        for (int r = 0; r < 4; ++r)
          outF[(size_t)(m0 + r) * N + n] = acc[i][j][r] + bv;
      }
    }
  }
}

// ---------------- causal flash attention ----------------
// Computes S^T = K*Q^T per 16-q wave so softmax row-reduce is shfl_xor(16,32),
// then O^T = V^T * P^T. q,k in [bh][t][64]; v in [bh][64][t] (transposed).
// Per-wave: 16 q columns; k-tiles of 32.

__global__ __launch_bounds__(256) void attn_kernel(
    const unsigned short* __restrict__ qB, const unsigned short* __restrict__ kB,
    const unsigned short* __restrict__ vB, unsigned short* __restrict__ yB) {
  const int lane = threadIdx.x & 63, w = threadIdx.x >> 6;
  const int g = lane >> 4, cx = lane & 15;
  const int bh = blockIdx.y;
  const int q0 = blockIdx.x * 64 + w * 16;
  const int qg = q0 + cx;
  const unsigned short* Qh = qB + (size_t)bh * 65536;
  const unsigned short* Kh = kB + (size_t)bh * 65536;
  const unsigned short* Vh = vB + (size_t)bh * 65536;

  // Q^T B-operand fragments (hoisted): lane holds Q[q0+cx][dh*32 + 8g..+7]
  bf16x8 qf0 = *(const bf16x8*)(Qh + qg * 64 + g * 8);
  bf16x8 qf1 = *(const bf16x8*)(Qh + qg * 64 + 32 + g * 8);

  f32x4 oacc[4] = {};
  float mrun = -__builtin_inff(), L = 0.0f;
  const float SC = 0.125f * 1.44269504088896340736f;  // 1/sqrt(64) * log2(e)
  const int ktmax = (q0 + 15) >> 5;
  for (int kt = 0; kt <= ktmax; ++kt) {
    const int kbase = kt * 32;
    f32x4 sa0 = {0.f, 0.f, 0.f, 0.f}, sa1 = {0.f, 0.f, 0.f, 0.f};
    {
      const unsigned short* kp0 = Kh + (size_t)(kbase + cx) * 64;
      const unsigned short* kp1 = Kh + (size_t)(kbase + 16 + cx) * 64;
      bf16x8 k00 = *(const bf16x8*)(kp0 + g * 8);
      bf16x8 k01 = *(const bf16x8*)(kp0 + 32 + g * 8);
      bf16x8 k10 = *(const bf16x8*)(kp1 + g * 8);
      bf16x8 k11 = *(const bf16x8*)(kp1 + 32 + g * 8);
      sa0 = __builtin_amdgcn_mfma_f32_16x16x32_bf16(k00, qf0, sa0, 0, 0, 0);
      sa0 = __builtin_amdgcn_mfma_f32_16x16x32_bf16(k01, qf1, sa0, 0, 0, 0);
      sa1 = __builtin_amdgcn_mfma_f32_16x16x32_bf16(k10, qf0, sa1, 0, 0, 0);
      sa1 = __builtin_amdgcn_mfma_f32_16x16x32_bf16(k11, qf1, sa1, 0, 0, 0);
    }
    // lane holds S^T[k=16*c2+4g+r][q=cx] ; base-2 domain
    float p[8];
    const bool notfull = (kbase + 31) > q0;
#pragma unroll
    for (int r = 0; r < 4; ++r) {
      float s0v = sa0[r] * SC;
      float s1v = sa1[r] * SC;
      if (notfull) {
        const int kg0 = kbase + (g << 2) + r;
        if (kg0 > qg) s0v = -__builtin_inff();
        if (kg0 + 16 > qg) s1v = -__builtin_inff();
      }
      p[r] = s0v;
      p[4 + r] = s1v;
    }
    float pm = fmaxf(fmaxf(fmaxf(p[0], p[1]), fmaxf(p[2], p[3])),
                     fmaxf(fmaxf(p[4], p[5]), fmaxf(p[6], p[7])));
    pm = fmaxf(pm, __shfl_xor(pm, 16));
    pm = fmaxf(pm, __shfl_xor(pm, 32));
    const float mnew = fmaxf(mrun, pm);
    const float cs = exp2f(mrun - mnew);
    mrun = mnew;
    float ps = 0.f;
#pragma unroll
    for (int e = 0; e < 8; ++e) {
      p[e] = exp2f(p[e] - mnew);
      ps += p[e];
    }
    ps += __shfl_xor(ps, 16);
    ps += __shfl_xor(ps, 32);
    L = L * cs + ps;
#pragma unroll
    for (int db = 0; db < 4; ++db) {
      oacc[db][0] *= cs; oacc[db][1] *= cs; oacc[db][2] *= cs; oacc[db][3] *= cs;
    }
    // build P^T B-operand: lane(g,cx) elem b needs P^T[8g+b][cx]
    // sources: lane s0=32*(g&1)+cx (b=0..3), s1=s0+16 (b=4..7); acc half c2=g>>1
    unsigned lo0 = (unsigned)f2bf(p[0]) | ((unsigned)f2bf(p[1]) << 16);
    unsigned hi0 = (unsigned)f2bf(p[2]) | ((unsigned)f2bf(p[3]) << 16);
    unsigned lo1 = (unsigned)f2bf(p[4]) | ((unsigned)f2bf(p[5]) << 16);
    unsigned hi1 = (unsigned)f2bf(p[6]) | ((unsigned)f2bf(p[7]) << 16);
    const int s0 = ((g & 1) << 5) + cx;
    const int s1 = s0 + 16;
    unsigned a0 = __shfl(lo0, s0), a1 = __shfl(hi0, s0), a2 = __shfl(lo0, s1), a3 = __shfl(hi0, s1);
    unsigned b0 = __shfl(lo1, s0), b1 = __shfl(hi1, s0), b2 = __shfl(lo1, s1), b3 = __shfl(hi1, s1);
    const bool ch = g >= 2;
    uint4e pw;
    pw[0] = ch ? b0 : a0; pw[1] = ch ? b1 : a1; pw[2] = ch ? b2 : a2; pw[3] = ch ? b3 : a3;
    const bf16x8 pf = __builtin_bit_cast(bf16x8, pw);
#pragma unroll
    for (int db = 0; db < 4; ++db) {
      bf16x8 vf = *(const bf16x8*)(Vh + (size_t)(db * 16 + cx) * 1024 + kbase + g * 8);
      oacc[db] = __builtin_amdgcn_mfma_f32_16x16x32_bf16(vf, pf, oacc[db], 0, 0, 0);
    }
  }
  const float inv = 1.0f / L;
  const int b = bh >> 4, h = bh & 15;
  unsigned short* yp = yB + (size_t)(b * 1024 + qg) * 1024 + h * 64;
#pragma unroll
  for (int db = 0; db < 4; ++db) {
    uint2 pv;
    pv.x = (unsigned)f2bf(oacc[db][0] * inv) | ((unsigned)f2bf(oacc[db][1] * inv) << 16);
    pv.y = (unsigned)f2bf(oacc[db][2] * inv) | ((unsigned)f2bf(oacc[db][3] * inv) << 16);
    *(uint2*)(yp + db * 16 + (g << 2)) = pv;
  }
}

// ---------------- launch ----------------

extern "C" void kernel_launch(void* const* d_in, const int* in_sizes, int n_in,
                              void* d_out, int out_size, void* d_ws, size_t ws_size,
                              hipStream_t stream) {
  (void)in_sizes; (void)n_in; (void)out_size; (void)ws_size;
  const float* x = (const float*)d_in[0];
  // d_in[1] = attn_mask (static causal tril) — implemented analytically
  const float* w_attn = (const float*)d_in[2];
  const float* b_attn = (const float*)d_in[3];
  const float* w_proj = (const float*)d_in[4];
  const float* b_proj = (const float*)d_in[5];
  float* out = (float*)d_out;

  char* ws = (char*)d_ws;
  unsigned short* xb     = (unsigned short*)(ws);
  unsigned short* wqkvT  = (unsigned short*)(ws + 16777216);
  unsigned short* wprojT = (unsigned short*)(ws + 23068672);
  unsigned short* qb     = (unsigned short*)(ws + 25165824);
  unsigned short* kb     = (unsigned short*)(ws + 41943040);
  unsigned short* vtb    = (unsigned short*)(ws + 58720256);
  unsigned short* yb     = (unsigned short*)(ws + 75497472);

  cvt_x_kernel<<<4096, 256, 0, stream>>>(x, xb);                       // 8.4M elems
  cvt_wT_kernel<<<dim3(96, 32), dim3(32, 8), 0, stream>>>(w_attn, wqkvT, 1024, 3072);
  cvt_wT_kernel<<<dim3(32, 32), dim3(32, 8), 0, stream>>>(w_proj, wprojT, 1024, 1024);

  gemm_kernel<0><<<dim3(24, 64), 256, 0, stream>>>(xb, wqkvT, b_attn, nullptr,
                                                   qb, kb, vtb, 8192, 3072, 1024);
  attn_kernel<<<dim3(16, 128), 256, 0, stream>>>(qb, kb, vtb, yb);
  gemm_kernel<1><<<dim3(8, 64), 256, 0, stream>>>(yb, wprojT, b_proj, out,
                                                  nullptr, nullptr, nullptr, 8192, 1024, 1024);
}

// Round 2
// 182.426 us; speedup vs baseline: 1.8866x; 1.8866x over previous
//
#include <hip/hip_runtime.h>

// ---------------------------------------------------------------------------
// CausalSelfAttention: qkv GEMM -> causal flash attention -> proj GEMM
// All matmuls via mfma_f32_16x16x32_bf16 (fp32 accum). bf16 tolerance per harness.
//
// ws layout (bytes):
//   x_bf16   [8192][1024]        @ 0          16,777,216
//   wqkvT    [3072][1024]        @ 16777216    6,291,456
//   wprojT   [1024][1024]        @ 23068672    2,097,152
//   q        [128][1024][64]     @ 25165824   16,777,216   (bh, t, d)  pre-scaled
//   k        [128][1024][64]     @ 41943040   16,777,216
//   vT       [128][64][1024]     @ 58720256   16,777,216   (bh, d, t)
//   y        [8192][1024]        @ 75497472   16,777,216
// total 92,274,688 bytes
// ---------------------------------------------------------------------------

typedef __bf16 bf16x8 __attribute__((ext_vector_type(8)));
typedef float f32x4 __attribute__((ext_vector_type(4)));
typedef unsigned uint4e __attribute__((ext_vector_type(4)));
typedef unsigned short ushort8e __attribute__((ext_vector_type(8)));

typedef __attribute__((address_space(1))) const unsigned as1_u32;
typedef __attribute__((address_space(3))) unsigned as3_u32;

#define NEG_INF (-__builtin_inff())

__device__ __forceinline__ unsigned short f2bf(float f) {
  unsigned u = __builtin_bit_cast(unsigned, f);
  u += 0x7fffu + ((u >> 16) & 1u);   // round-to-nearest-even (finite inputs)
  return (unsigned short)(u >> 16);
}

// ---------------- conversion kernels ----------------

__global__ void cvt_x_kernel(const float* __restrict__ in, unsigned short* __restrict__ out) {
  size_t i = (size_t)(blockIdx.x * 256 + threadIdx.x) * 8;
  float4 a = *(const float4*)(in + i);
  float4 b = *(const float4*)(in + i + 4);
  ushort8e o;
  o[0] = f2bf(a.x); o[1] = f2bf(a.y); o[2] = f2bf(a.z); o[3] = f2bf(a.w);
  o[4] = f2bf(b.x); o[5] = f2bf(b.y); o[6] = f2bf(b.z); o[7] = f2bf(b.w);
  *(ushort8e*)(out + i) = o;
}

// w [K][N] fp32 -> wT [N][K] bf16, 32x32 LDS tile transpose
__global__ void cvt_wT_kernel(const float* __restrict__ w, unsigned short* __restrict__ wT,
                              int K, int N) {
  __shared__ float tile[32][33];
  const int n0 = blockIdx.x * 32, k0 = blockIdx.y * 32;
  const int tx = threadIdx.x, ty = threadIdx.y;
#pragma unroll
  for (int i = 0; i < 32; i += 8)
    tile[ty + i][tx] = w[(size_t)(k0 + ty + i) * N + n0 + tx];
  __syncthreads();
#pragma unroll
  for (int i = 0; i < 32; i += 8)
    wT[(size_t)(n0 + ty + i) * K + k0 + tx] = f2bf(tile[tx][ty + i]);
}

// ---------------- GEMM: C[M,N] = A[M,K](bf16) * BT[N,K](bf16)^T + bias ----------------
// EPI 0: scatter to q/k/vT bf16 buffers (qkv GEMM); q pre-scaled by 0.125*log2(e)
// EPI 1: fp32 store to outF (proj GEMM)

#define BM 128
#define BN 128
#define BK 32

template <int EPI>
__global__ __launch_bounds__(256) void gemm_kernel(
    const unsigned short* __restrict__ A, const unsigned short* __restrict__ BT,
    const float* __restrict__ bias, float* __restrict__ outF,
    unsigned short* __restrict__ qO, unsigned short* __restrict__ kO,
    unsigned short* __restrict__ vO, int M, int N, int K) {
  __shared__ __align__(16) unsigned short As[BM * BK];
  __shared__ __align__(16) unsigned short Bs[BN * BK];
  const int tid = threadIdx.x;
  const int w = tid >> 6, lane = tid & 63;
  const int g = lane >> 4, cx = lane & 15;
  const int bm = blockIdx.y * BM, bn = blockIdx.x * BN;
  const int wm = (w >> 1) * 64, wn = (w & 1) * 64;

  const int sr = tid >> 2, sc = tid & 3;
  const int swz = (sr >> 1) & 3;
  const unsigned short* ga0 = A + (size_t)(bm + sr) * K + sc * 8;
  const unsigned short* ga1 = A + (size_t)(bm + sr + 64) * K + sc * 8;
  const unsigned short* gb0 = BT + (size_t)(bn + sr) * K + sc * 8;
  const unsigned short* gb1 = BT + (size_t)(bn + sr + 64) * K + sc * 8;
  unsigned short* la0 = &As[sr * BK + ((sc ^ swz) << 3)];
  unsigned short* la1 = &As[(sr + 64) * BK + ((sc ^ swz) << 3)];
  unsigned short* lb0 = &Bs[sr * BK + ((sc ^ swz) << 3)];
  unsigned short* lb1 = &Bs[(sr + 64) * BK + ((sc ^ swz) << 3)];

  const unsigned short* ap[4];
  const unsigned short* bp[4];
#pragma unroll
  for (int i = 0; i < 4; ++i) {
    const int R = wm + i * 16 + cx;
    ap[i] = &As[R * BK + ((g ^ ((R >> 1) & 3)) << 3)];
    const int Rb = wn + i * 16 + cx;
    bp[i] = &Bs[Rb * BK + ((g ^ ((Rb >> 1) & 3)) << 3)];
  }

  f32x4 acc[4][4] = {};

  for (int kt = 0; kt < K; kt += BK) {
    uint4 va0 = *(const uint4*)(ga0 + kt);
    uint4 va1 = *(const uint4*)(ga1 + kt);
    uint4 vb0 = *(const uint4*)(gb0 + kt);
    uint4 vb1 = *(const uint4*)(gb1 + kt);
    *(uint4*)la0 = va0;
    *(uint4*)la1 = va1;
    *(uint4*)lb0 = vb0;
    *(uint4*)lb1 = vb1;
    __syncthreads();
    bf16x8 af[4], bfr[4];
#pragma unroll
    for (int i = 0; i < 4; ++i) {
      af[i] = *(const bf16x8*)ap[i];
      bfr[i] = *(const bf16x8*)bp[i];
    }
#pragma unroll
    for (int i = 0; i < 4; ++i)
#pragma unroll
      for (int j = 0; j < 4; ++j)
        acc[i][j] = __builtin_amdgcn_mfma_f32_16x16x32_bf16(af[i], bfr[j], acc[i][j], 0, 0, 0);
    __syncthreads();
  }

  if (EPI == 0) {
#pragma unroll
    for (int i = 0; i < 4; ++i) {
      const int m0 = bm + wm + i * 16 + (g << 2);
      const int b = m0 >> 10, t0 = m0 & 1023;
#pragma unroll
      for (int j = 0; j < 4; ++j) {
        const int n = bn + wn + j * 16 + cx;
        const float bv = bias[n];
        const int which = n >> 10, rem = n & 1023;
        const int h = rem >> 6, d = rem & 63;
        const int bh = b * 16 + h;
        if (which == 2) {
          uint2 pv;
          pv.x = (unsigned)f2bf(acc[i][j][0] + bv) | ((unsigned)f2bf(acc[i][j][1] + bv) << 16);
          pv.y = (unsigned)f2bf(acc[i][j][2] + bv) | ((unsigned)f2bf(acc[i][j][3] + bv) << 16);
          *(uint2*)(vO + ((size_t)bh * 64 + d) * 1024 + t0) = pv;
        } else {
          unsigned short* dst = (which == 0 ? qO : kO);
          const float scl = (which == 0) ? 0.18033688011112042f : 1.0f;  // 0.125*log2(e)
#pragma unroll
          for (int r = 0; r < 4; ++r)
            dst[((size_t)bh * 1024 + (t0 + r)) * 64 + d] = f2bf((acc[i][j][r] + bv) * scl);
        }
      }
    }
  } else {
#pragma unroll
    for (int i = 0; i < 4; ++i) {
      const int m0 = bm + wm + i * 16 + (g << 2);
#pragma unroll
      for (int j = 0; j < 4; ++j) {
        const int n = bn + wn + j * 16 + cx;
        const float bv = bias[n];
#pragma unroll
        for (int r = 0; r < 4; ++r)
          outF[(size_t)(m0 + r) * N + n] = acc[i][j][r] + bv;
      }
    }
  }
}

// ---------------- causal flash attention (LDS-staged, double-buffered) ----------------
// Block: 4 waves, 128 q rows (wave w owns q-subtiles qb0+w*16 and qb0+64+w*16).
// K/V^T tiles (64 rows x 64 cols bf16) staged via global_load_lds with
// pre-swizzled source (chunk ^= row&7); ds_read_b128 reads apply same XOR.
// S^T = K*Q^T (swapped) -> softmax reduce over lanes {cx, cx+16, cx+32, cx+48};
// P^T rebuilt in-register via shuffles; O^T = V^T * P^T.

__global__ __launch_bounds__(256) void attn_kernel(
    const unsigned short* __restrict__ qB, const unsigned short* __restrict__ kB,
    const unsigned short* __restrict__ vB, unsigned short* __restrict__ yB) {
  __shared__ __align__(16) unsigned short Ks[2][64 * 64];
  __shared__ __align__(16) unsigned short Vs[2][64 * 64];
  const int lane = threadIdx.x & 63, w = threadIdx.x >> 6;
  const int g = lane >> 4, cx = lane & 15;
  const int bh = blockIdx.x;           // head-major: head pinned to XCD bh%8
  const int qt = 7 - blockIdx.y;       // biggest-work q-tiles dispatch first
  const int qb0 = qt * 128;
  const int nt = qt * 2 + 2;           // number of 64-wide k tiles
  const unsigned short* Qh = qB + (size_t)bh * 65536;
  const unsigned short* Kh = kB + (size_t)bh * 65536;
  const unsigned short* Vh = vB + (size_t)bh * 65536;

  const int qsb0 = qb0 + w * 16, qsb1 = qb0 + 64 + w * 16;

  // Q^T B-operand fragments (pre-scaled by 0.125*log2e at qkv epilogue)
  bf16x8 qf[2][2];
#pragma unroll
  for (int s = 0; s < 2; ++s) {
    const int qq = (s ? qsb1 : qsb0) + cx;
#pragma unroll
    for (int h = 0; h < 2; ++h)
      qf[s][h] = *(const bf16x8*)(Qh + (size_t)qq * 64 + h * 32 + g * 8);
  }

  f32x4 oacc[2][4] = {};
  float mrun0 = NEG_INF, mrun1 = NEG_INF, L0 = 0.f, L1 = 0.f;

  const int srl = lane >> 3, sch = lane & 7;  // staging: row-in-8, 16B chunk

  auto stage = [&](int t, int buf) {
#pragma unroll
    for (int i = 0; i < 2; ++i) {
      const int row = w * 16 + i * 8 + srl;
      const int csw = (sch ^ (row & 7)) << 3;
      const unsigned short* gk = Kh + (size_t)(t * 64 + row) * 64 + csw;
      __builtin_amdgcn_global_load_lds((as1_u32*)(const void*)gk,
          (as3_u32*)(void*)&Ks[buf][(w * 16 + i * 8) * 64], 16, 0, 0);
      const unsigned short* gv = Vh + (size_t)row * 1024 + t * 64 + csw;
      __builtin_amdgcn_global_load_lds((as1_u32*)(const void*)gv,
          (as3_u32*)(void*)&Vs[buf][(w * 16 + i * 8) * 64], 16, 0, 0);
    }
  };

  auto mkpf = [&](const float* pp) -> bf16x8 {
    unsigned lo0 = (unsigned)f2bf(pp[0]) | ((unsigned)f2bf(pp[1]) << 16);
    unsigned hi0 = (unsigned)f2bf(pp[2]) | ((unsigned)f2bf(pp[3]) << 16);
    unsigned lo1 = (unsigned)f2bf(pp[4]) | ((unsigned)f2bf(pp[5]) << 16);
    unsigned hi1 = (unsigned)f2bf(pp[6]) | ((unsigned)f2bf(pp[7]) << 16);
    const int s0 = ((g & 1) << 5) + cx, s1 = s0 + 16;
    unsigned a0 = __shfl(lo0, s0), a1 = __shfl(hi0, s0), a2 = __shfl(lo0, s1), a3 = __shfl(hi0, s1);
    unsigned b0 = __shfl(lo1, s0), b1 = __shfl(hi1, s0), b2 = __shfl(lo1, s1), b3 = __shfl(hi1, s1);
    const bool chh = g >= 2;
    uint4e pw;
    pw[0] = chh ? b0 : a0; pw[1] = chh ? b1 : a1; pw[2] = chh ? b2 : a2; pw[3] = chh ? b3 : a3;
    return __builtin_bit_cast(bf16x8, pw);
  };

  stage(0, 0);
  asm volatile("s_waitcnt vmcnt(0)" ::: "memory");
  __builtin_amdgcn_s_barrier();
  asm volatile("" ::: "memory");

  for (int t = 0; t < nt; ++t) {
    const int buf = t & 1;
    if (t + 1 < nt) stage(t + 1, buf ^ 1);   // prefetch overlaps compute
    const int k0 = t * 64;
    const bool act0 = k0 <= qsb0 + 15;       // wave-uniform

    // --- K fragments + QK^T (S^T, base-2 scaled domain) ---
    bf16x8 kf[4][2];
#pragma unroll
    for (int kc = 0; kc < 4; ++kc) {
      const int row = kc * 16 + cx;
#pragma unroll
      for (int h = 0; h < 2; ++h)
        kf[kc][h] = *(const bf16x8*)&Ks[buf][row * 64 + (((h * 4 + g) ^ (row & 7)) << 3)];
    }
    f32x4 sa[2][4];
#pragma unroll
    for (int kc = 0; kc < 4; ++kc) {
      f32x4 z = {0.f, 0.f, 0.f, 0.f};
      sa[1][kc] = __builtin_amdgcn_mfma_f32_16x16x32_bf16(kf[kc][0], qf[1][0], z, 0, 0, 0);
      sa[1][kc] = __builtin_amdgcn_mfma_f32_16x16x32_bf16(kf[kc][1], qf[1][1], sa[1][kc], 0, 0, 0);
    }
    if (act0) {
#pragma unroll
      for (int kc = 0; kc < 4; ++kc) {
        f32x4 z = {0.f, 0.f, 0.f, 0.f};
        sa[0][kc] = __builtin_amdgcn_mfma_f32_16x16x32_bf16(kf[kc][0], qf[0][0], z, 0, 0, 0);
        sa[0][kc] = __builtin_amdgcn_mfma_f32_16x16x32_bf16(kf[kc][1], qf[0][1], sa[0][kc], 0, 0, 0);
      }
    }

    // --- V fragments ---
    bf16x8 vf[4][2];
#pragma unroll
    for (int db = 0; db < 4; ++db) {
      const int row = db * 16 + cx;
#pragma unroll
      for (int h = 0; h < 2; ++h)
        vf[db][h] = *(const bf16x8*)&Vs[buf][row * 64 + (((h * 4 + g) ^ (row & 7)) << 3)];
    }

    // --- softmax + PV per active q-subtile ---
#pragma unroll
    for (int s = 0; s < 2; ++s) {
      if (s == 0 && !act0) continue;
      const int qsb = s ? qsb1 : qsb0;
      const int qg = qsb + cx;
      float& mrun = s ? mrun1 : mrun0;
      float& L = s ? L1 : L0;
      float p[16];
      const bool straddle = (k0 + 63) > qsb;
#pragma unroll
      for (int kc = 0; kc < 4; ++kc)
#pragma unroll
        for (int r = 0; r < 4; ++r) {
          float v = sa[s][kc][r];
          if (straddle && (k0 + kc * 16 + (g << 2) + r) > qg) v = NEG_INF;
          p[kc * 4 + r] = v;
        }
      float m01 = fmaxf(fmaxf(p[0], p[1]), fmaxf(p[2], p[3]));
      float m23 = fmaxf(fmaxf(p[4], p[5]), fmaxf(p[6], p[7]));
      float m45 = fmaxf(fmaxf(p[8], p[9]), fmaxf(p[10], p[11]));
      float m67 = fmaxf(fmaxf(p[12], p[13]), fmaxf(p[14], p[15]));
      float pm = fmaxf(fmaxf(m01, m23), fmaxf(m45, m67));
      pm = fmaxf(pm, __shfl_xor(pm, 16));
      pm = fmaxf(pm, __shfl_xor(pm, 32));
      const float mnew = fmaxf(mrun, pm);
      const float cs = __builtin_amdgcn_exp2f(mrun - mnew);
      mrun = mnew;
      float ps = 0.f;
#pragma unroll
      for (int e = 0; e < 16; ++e) {
        p[e] = __builtin_amdgcn_exp2f(p[e] - mnew);
        ps += p[e];
      }
      ps += __shfl_xor(ps, 16);
      ps += __shfl_xor(ps, 32);
      L = L * cs + ps;
#pragma unroll
      for (int db = 0; db < 4; ++db) {
        oacc[s][db][0] *= cs; oacc[s][db][1] *= cs;
        oacc[s][db][2] *= cs; oacc[s][db][3] *= cs;
      }
      const bf16x8 pf0 = mkpf(p);
      const bf16x8 pf1 = mkpf(p + 8);
#pragma unroll
      for (int db = 0; db < 4; ++db) {
        oacc[s][db] = __builtin_amdgcn_mfma_f32_16x16x32_bf16(vf[db][0], pf0, oacc[s][db], 0, 0, 0);
        oacc[s][db] = __builtin_amdgcn_mfma_f32_16x16x32_bf16(vf[db][1], pf1, oacc[s][db], 0, 0, 0);
      }
    }

    asm volatile("s_waitcnt vmcnt(0)" ::: "memory");  // next tile arrived
    __builtin_amdgcn_s_barrier();
    asm volatile("" ::: "memory");                    // keep next reads below
  }

  const int b = bh >> 4, h = bh & 15;
#pragma unroll
  for (int s = 0; s < 2; ++s) {
    const float inv = 1.0f / (s ? L1 : L0);
    const int qg = (s ? qsb1 : qsb0) + cx;
    unsigned short* yp = yB + (size_t)(b * 1024 + qg) * 1024 + h * 64;
#pragma unroll
    for (int db = 0; db < 4; ++db) {
      uint2 pv;
      pv.x = (unsigned)f2bf(oacc[s][db][0] * inv) | ((unsigned)f2bf(oacc[s][db][1] * inv) << 16);
      pv.y = (unsigned)f2bf(oacc[s][db][2] * inv) | ((unsigned)f2bf(oacc[s][db][3] * inv) << 16);
      *(uint2*)(yp + db * 16 + (g << 2)) = pv;
    }
  }
}

// ---------------- launch ----------------

extern "C" void kernel_launch(void* const* d_in, const int* in_sizes, int n_in,
                              void* d_out, int out_size, void* d_ws, size_t ws_size,
                              hipStream_t stream) {
  (void)in_sizes; (void)n_in; (void)out_size; (void)ws_size;
  const float* x = (const float*)d_in[0];
  // d_in[1] = attn_mask (static causal tril) — implemented analytically
  const float* w_attn = (const float*)d_in[2];
  const float* b_attn = (const float*)d_in[3];
  const float* w_proj = (const float*)d_in[4];
  const float* b_proj = (const float*)d_in[5];
  float* out = (float*)d_out;

  char* ws = (char*)d_ws;
  unsigned short* xb     = (unsigned short*)(ws);
  unsigned short* wqkvT  = (unsigned short*)(ws + 16777216);
  unsigned short* wprojT = (unsigned short*)(ws + 23068672);
  unsigned short* qb     = (unsigned short*)(ws + 25165824);
  unsigned short* kb     = (unsigned short*)(ws + 41943040);
  unsigned short* vtb    = (unsigned short*)(ws + 58720256);
  unsigned short* yb     = (unsigned short*)(ws + 75497472);

  cvt_x_kernel<<<4096, 256, 0, stream>>>(x, xb);
  cvt_wT_kernel<<<dim3(96, 32), dim3(32, 8), 0, stream>>>(w_attn, wqkvT, 1024, 3072);
  cvt_wT_kernel<<<dim3(32, 32), dim3(32, 8), 0, stream>>>(w_proj, wprojT, 1024, 1024);

  gemm_kernel<0><<<dim3(24, 64), 256, 0, stream>>>(xb, wqkvT, b_attn, nullptr,
                                                   qb, kb, vtb, 8192, 3072, 1024);
  attn_kernel<<<dim3(128, 8), 256, 0, stream>>>(qb, kb, vtb, yb);
  gemm_kernel<1><<<dim3(8, 64), 256, 0, stream>>>(yb, wprojT, b_proj, out,
                                                  nullptr, nullptr, nullptr, 8192, 1024, 1024);
}

// Round 3
// 180.033 us; speedup vs baseline: 1.9117x; 1.0133x over previous
//
#include <hip/hip_runtime.h>

// ---------------------------------------------------------------------------
// CausalSelfAttention: qkv GEMM -> causal flash attention -> proj GEMM
// All matmuls via mfma_f32_16x16x32_bf16 (fp32 accum). bf16 tolerance per harness.
//
// ws layout (bytes):
//   x_bf16   [8192][1024]        @ 0          16,777,216
//   wqkvT    [3072][1024]        @ 16777216    6,291,456
//   wprojT   [1024][1024]        @ 23068672    2,097,152
//   q        [128][1024][64]     @ 25165824   16,777,216   (bh, t, d)  pre-scaled
//   k        [128][1024][64]     @ 41943040   16,777,216
//   vT       [128][64][1024]     @ 58720256   16,777,216   (bh, d, t)
//   y        [8192][1024]        @ 75497472   16,777,216
// total 92,274,688 bytes
// ---------------------------------------------------------------------------

typedef __bf16 bf16x8 __attribute__((ext_vector_type(8)));
typedef float f32x4 __attribute__((ext_vector_type(4)));
typedef unsigned uint4e __attribute__((ext_vector_type(4)));
typedef unsigned short ushort8e __attribute__((ext_vector_type(8)));

typedef __attribute__((address_space(1))) const unsigned as1_u32;
typedef __attribute__((address_space(3))) unsigned as3_u32;

#define NEG_INF (-__builtin_inff())

__device__ __forceinline__ unsigned short f2bf(float f) {
  unsigned u = __builtin_bit_cast(unsigned, f);
  u += 0x7fffu + ((u >> 16) & 1u);   // round-to-nearest-even (finite inputs)
  return (unsigned short)(u >> 16);
}

// ---------------- conversion kernels ----------------

__global__ void cvt_x_kernel(const float* __restrict__ in, unsigned short* __restrict__ out) {
  size_t i = (size_t)(blockIdx.x * 256 + threadIdx.x) * 8;
  float4 a = *(const float4*)(in + i);
  float4 b = *(const float4*)(in + i + 4);
  ushort8e o;
  o[0] = f2bf(a.x); o[1] = f2bf(a.y); o[2] = f2bf(a.z); o[3] = f2bf(a.w);
  o[4] = f2bf(b.x); o[5] = f2bf(b.y); o[6] = f2bf(b.z); o[7] = f2bf(b.w);
  *(ushort8e*)(out + i) = o;
}

// w [K][N] fp32 -> wT [N][K] bf16, 32x32 LDS tile transpose
__global__ void cvt_wT_kernel(const float* __restrict__ w, unsigned short* __restrict__ wT,
                              int K, int N) {
  __shared__ float tile[32][33];
  const int n0 = blockIdx.x * 32, k0 = blockIdx.y * 32;
  const int tx = threadIdx.x, ty = threadIdx.y;
#pragma unroll
  for (int i = 0; i < 32; i += 8)
    tile[ty + i][tx] = w[(size_t)(k0 + ty + i) * N + n0 + tx];
  __syncthreads();
#pragma unroll
  for (int i = 0; i < 32; i += 8)
    wT[(size_t)(n0 + ty + i) * K + k0 + tx] = f2bf(tile[tx][ty + i]);
}

// ---------------- GEMM: C[M,N] = A[M,K](bf16) * BT[N,K](bf16)^T + bias ----------------
// Staging via global_load_lds (16B/lane, linear LDS dest = wave base + lane*16).
// LDS chunk swizzle (chunk ^= (row>>1)&3) applied on the GLOBAL source address
// (involution), reads apply the same XOR -> identical layout to reg-staged ver.
// EPI 0: scatter to q/k/vT bf16 buffers (qkv GEMM); q pre-scaled by 0.125*log2(e)
// EPI 1: fp32 store to outF (proj GEMM)

#define BM 128
#define BN 128
#define BK 32

template <int EPI>
__global__ __launch_bounds__(256) void gemm_kernel(
    const unsigned short* __restrict__ A, const unsigned short* __restrict__ BT,
    const float* __restrict__ bias, float* __restrict__ outF,
    unsigned short* __restrict__ qO, unsigned short* __restrict__ kO,
    unsigned short* __restrict__ vO, int M, int N, int K) {
  __shared__ __align__(16) unsigned short As[BM * BK];
  __shared__ __align__(16) unsigned short Bs[BN * BK];
  const int tid = threadIdx.x;
  const int w = tid >> 6, lane = tid & 63;
  const int g = lane >> 4, cx = lane & 15;
  const int bm = blockIdx.y * BM, bn = blockIdx.x * BN;
  const int wm = (w >> 1) * 64, wn = (w & 1) * 64;

  // staging: wave w covers LDS rows [w*16, w*16+16) and [w*16+64, +16).
  // lane i -> row base+ (i>>2), 16B chunk (i&3); global chunk pre-swizzled.
  const int sr = (w << 4) + (lane >> 2);               // row for call 0
  const int csw = ((lane & 3) ^ ((sr >> 1) & 3)) << 3; // elem offset (same for sr+64)
  const unsigned short* ga0 = A + (size_t)(bm + sr) * K + csw;
  const unsigned short* ga1 = A + (size_t)(bm + sr + 64) * K + csw;
  const unsigned short* gb0 = BT + (size_t)(bn + sr) * K + csw;
  const unsigned short* gb1 = BT + (size_t)(bn + sr + 64) * K + csw;
  unsigned short* la0 = &As[(w << 4) * BK];
  unsigned short* la1 = &As[((w << 4) + 64) * BK];
  unsigned short* lb0 = &Bs[(w << 4) * BK];
  unsigned short* lb1 = &Bs[((w << 4) + 64) * BK];

  // fragment read pointers (swizzled chunk = g ^ ((row>>1)&3))
  const unsigned short* ap[4];
  const unsigned short* bp[4];
#pragma unroll
  for (int i = 0; i < 4; ++i) {
    const int R = wm + i * 16 + cx;
    ap[i] = &As[R * BK + ((g ^ ((R >> 1) & 3)) << 3)];
    const int Rb = wn + i * 16 + cx;
    bp[i] = &Bs[Rb * BK + ((g ^ ((Rb >> 1) & 3)) << 3)];
  }

  f32x4 acc[4][4] = {};

  for (int kt = 0; kt < K; kt += BK) {
    __builtin_amdgcn_global_load_lds((as1_u32*)(const void*)(ga0 + kt),
                                     (as3_u32*)(void*)la0, 16, 0, 0);
    __builtin_amdgcn_global_load_lds((as1_u32*)(const void*)(ga1 + kt),
                                     (as3_u32*)(void*)la1, 16, 0, 0);
    __builtin_amdgcn_global_load_lds((as1_u32*)(const void*)(gb0 + kt),
                                     (as3_u32*)(void*)lb0, 16, 0, 0);
    __builtin_amdgcn_global_load_lds((as1_u32*)(const void*)(gb1 + kt),
                                     (as3_u32*)(void*)lb1, 16, 0, 0);
    __syncthreads();   // drains vmcnt (global_load_lds) + barrier
    bf16x8 af[4], bfr[4];
#pragma unroll
    for (int i = 0; i < 4; ++i) {
      af[i] = *(const bf16x8*)ap[i];
      bfr[i] = *(const bf16x8*)bp[i];
    }
#pragma unroll
    for (int i = 0; i < 4; ++i)
#pragma unroll
      for (int j = 0; j < 4; ++j)
        acc[i][j] = __builtin_amdgcn_mfma_f32_16x16x32_bf16(af[i], bfr[j], acc[i][j], 0, 0, 0);
    __syncthreads();   // all reads done before next stage overwrites
  }

  if (EPI == 0) {
#pragma unroll
    for (int i = 0; i < 4; ++i) {
      const int m0 = bm + wm + i * 16 + (g << 2);
      const int b = m0 >> 10, t0 = m0 & 1023;
#pragma unroll
      for (int j = 0; j < 4; ++j) {
        const int n = bn + wn + j * 16 + cx;
        const float bv = bias[n];
        const int which = n >> 10, rem = n & 1023;
        const int h = rem >> 6, d = rem & 63;
        const int bh = b * 16 + h;
        if (which == 2) {
          uint2 pv;
          pv.x = (unsigned)f2bf(acc[i][j][0] + bv) | ((unsigned)f2bf(acc[i][j][1] + bv) << 16);
          pv.y = (unsigned)f2bf(acc[i][j][2] + bv) | ((unsigned)f2bf(acc[i][j][3] + bv) << 16);
          *(uint2*)(vO + ((size_t)bh * 64 + d) * 1024 + t0) = pv;
        } else {
          unsigned short* dst = (which == 0 ? qO : kO);
          const float scl = (which == 0) ? 0.18033688011112042f : 1.0f;  // 0.125*log2(e)
#pragma unroll
          for (int r = 0; r < 4; ++r)
            dst[((size_t)bh * 1024 + (t0 + r)) * 64 + d] = f2bf((acc[i][j][r] + bv) * scl);
        }
      }
    }
  } else {
#pragma unroll
    for (int i = 0; i < 4; ++i) {
      const int m0 = bm + wm + i * 16 + (g << 2);
#pragma unroll
      for (int j = 0; j < 4; ++j) {
        const int n = bn + wn + j * 16 + cx;
        const float bv = bias[n];
#pragma unroll
        for (int r = 0; r < 4; ++r)
          outF[(size_t)(m0 + r) * N + n] = acc[i][j][r] + bv;
      }
    }
  }
}

// ---------------- causal flash attention (LDS-staged, double-buffered) ----------------
// Block: 4 waves, 128 q rows (wave w owns q-subtiles qb0+w*16 and qb0+64+w*16).
// K/V^T tiles (64 rows x 64 cols bf16) staged via global_load_lds with
// pre-swizzled source (chunk ^= row&7); ds_read_b128 reads apply same XOR.
// S^T = K*Q^T (swapped) -> softmax reduce over lanes {cx, cx+16, cx+32, cx+48};
// P^T rebuilt in-register via shuffles; O^T = V^T * P^T.

__global__ __launch_bounds__(256) void attn_kernel(
    const unsigned short* __restrict__ qB, const unsigned short* __restrict__ kB,
    const unsigned short* __restrict__ vB, unsigned short* __restrict__ yB) {
  __shared__ __align__(16) unsigned short Ks[2][64 * 64];
  __shared__ __align__(16) unsigned short Vs[2][64 * 64];
  const int lane = threadIdx.x & 63, w = threadIdx.x >> 6;
  const int g = lane >> 4, cx = lane & 15;
  const int bh = blockIdx.x;           // head-major: head pinned to XCD bh%8
  const int qt = 7 - blockIdx.y;       // biggest-work q-tiles dispatch first
  const int qb0 = qt * 128;
  const int nt = qt * 2 + 2;           // number of 64-wide k tiles
  const unsigned short* Qh = qB + (size_t)bh * 65536;
  const unsigned short* Kh = kB + (size_t)bh * 65536;
  const unsigned short* Vh = vB + (size_t)bh * 65536;

  const int qsb0 = qb0 + w * 16, qsb1 = qb0 + 64 + w * 16;

  // Q^T B-operand fragments (pre-scaled by 0.125*log2e at qkv epilogue)
  bf16x8 qf[2][2];
#pragma unroll
  for (int s = 0; s < 2; ++s) {
    const int qq = (s ? qsb1 : qsb0) + cx;
#pragma unroll
    for (int h = 0; h < 2; ++h)
      qf[s][h] = *(const bf16x8*)(Qh + (size_t)qq * 64 + h * 32 + g * 8);
  }

  f32x4 oacc[2][4] = {};
  float mrun0 = NEG_INF, mrun1 = NEG_INF, L0 = 0.f, L1 = 0.f;

  const int srl = lane >> 3, sch = lane & 7;  // staging: row-in-8, 16B chunk

  auto stage = [&](int t, int buf) {
#pragma unroll
    for (int i = 0; i < 2; ++i) {
      const int row = w * 16 + i * 8 + srl;
      const int csw = (sch ^ (row & 7)) << 3;
      const unsigned short* gk = Kh + (size_t)(t * 64 + row) * 64 + csw;
      __builtin_amdgcn_global_load_lds((as1_u32*)(const void*)gk,
          (as3_u32*)(void*)&Ks[buf][(w * 16 + i * 8) * 64], 16, 0, 0);
      const unsigned short* gv = Vh + (size_t)row * 1024 + t * 64 + csw;
      __builtin_amdgcn_global_load_lds((as1_u32*)(const void*)gv,
          (as3_u32*)(void*)&Vs[buf][(w * 16 + i * 8) * 64], 16, 0, 0);
    }
  };

  auto mkpf = [&](const float* pp) -> bf16x8 {
    unsigned lo0 = (unsigned)f2bf(pp[0]) | ((unsigned)f2bf(pp[1]) << 16);
    unsigned hi0 = (unsigned)f2bf(pp[2]) | ((unsigned)f2bf(pp[3]) << 16);
    unsigned lo1 = (unsigned)f2bf(pp[4]) | ((unsigned)f2bf(pp[5]) << 16);
    unsigned hi1 = (unsigned)f2bf(pp[6]) | ((unsigned)f2bf(pp[7]) << 16);
    const int s0 = ((g & 1) << 5) + cx, s1 = s0 + 16;
    unsigned a0 = __shfl(lo0, s0), a1 = __shfl(hi0, s0), a2 = __shfl(lo0, s1), a3 = __shfl(hi0, s1);
    unsigned b0 = __shfl(lo1, s0), b1 = __shfl(hi1, s0), b2 = __shfl(lo1, s1), b3 = __shfl(hi1, s1);
    const bool chh = g >= 2;
    uint4e pw;
    pw[0] = chh ? b0 : a0; pw[1] = chh ? b1 : a1; pw[2] = chh ? b2 : a2; pw[3] = chh ? b3 : a3;
    return __builtin_bit_cast(bf16x8, pw);
  };

  stage(0, 0);
  asm volatile("s_waitcnt vmcnt(0)" ::: "memory");
  __builtin_amdgcn_s_barrier();
  asm volatile("" ::: "memory");

  for (int t = 0; t < nt; ++t) {
    const int buf = t & 1;
    if (t + 1 < nt) stage(t + 1, buf ^ 1);   // prefetch overlaps compute
    const int k0 = t * 64;
    const bool act0 = k0 <= qsb0 + 15;       // wave-uniform

    // --- K fragments + QK^T (S^T, base-2 scaled domain) ---
    bf16x8 kf[4][2];
#pragma unroll
    for (int kc = 0; kc < 4; ++kc) {
      const int row = kc * 16 + cx;
#pragma unroll
      for (int h = 0; h < 2; ++h)
        kf[kc][h] = *(const bf16x8*)&Ks[buf][row * 64 + (((h * 4 + g) ^ (row & 7)) << 3)];
    }
    f32x4 sa[2][4];
#pragma unroll
    for (int kc = 0; kc < 4; ++kc) {
      f32x4 z = {0.f, 0.f, 0.f, 0.f};
      sa[1][kc] = __builtin_amdgcn_mfma_f32_16x16x32_bf16(kf[kc][0], qf[1][0], z, 0, 0, 0);
      sa[1][kc] = __builtin_amdgcn_mfma_f32_16x16x32_bf16(kf[kc][1], qf[1][1], sa[1][kc], 0, 0, 0);
    }
    if (act0) {
#pragma unroll
      for (int kc = 0; kc < 4; ++kc) {
        f32x4 z = {0.f, 0.f, 0.f, 0.f};
        sa[0][kc] = __builtin_amdgcn_mfma_f32_16x16x32_bf16(kf[kc][0], qf[0][0], z, 0, 0, 0);
        sa[0][kc] = __builtin_amdgcn_mfma_f32_16x16x32_bf16(kf[kc][1], qf[0][1], sa[0][kc], 0, 0, 0);
      }
    }

    // --- V fragments ---
    bf16x8 vf[4][2];
#pragma unroll
    for (int db = 0; db < 4; ++db) {
      const int row = db * 16 + cx;
#pragma unroll
      for (int h = 0; h < 2; ++h)
        vf[db][h] = *(const bf16x8*)&Vs[buf][row * 64 + (((h * 4 + g) ^ (row & 7)) << 3)];
    }

    // --- softmax + PV per active q-subtile ---
#pragma unroll
    for (int s = 0; s < 2; ++s) {
      if (s == 0 && !act0) continue;
      const int qsb = s ? qsb1 : qsb0;
      const int qg = qsb + cx;
      float& mrun = s ? mrun1 : mrun0;
      float& L = s ? L1 : L0;
      float p[16];
      const bool straddle = (k0 + 63) > qsb;
#pragma unroll
      for (int kc = 0; kc < 4; ++kc)
#pragma unroll
        for (int r = 0; r < 4; ++r) {
          float v = sa[s][kc][r];
          if (straddle && (k0 + kc * 16 + (g << 2) + r) > qg) v = NEG_INF;
          p[kc * 4 + r] = v;
        }
      float m01 = fmaxf(fmaxf(p[0], p[1]), fmaxf(p[2], p[3]));
      float m23 = fmaxf(fmaxf(p[4], p[5]), fmaxf(p[6], p[7]));
      float m45 = fmaxf(fmaxf(p[8], p[9]), fmaxf(p[10], p[11]));
      float m67 = fmaxf(fmaxf(p[12], p[13]), fmaxf(p[14], p[15]));
      float pm = fmaxf(fmaxf(m01, m23), fmaxf(m45, m67));
      pm = fmaxf(pm, __shfl_xor(pm, 16));
      pm = fmaxf(pm, __shfl_xor(pm, 32));
      const float mnew = fmaxf(mrun, pm);
      const float cs = __builtin_amdgcn_exp2f(mrun - mnew);
      mrun = mnew;
      float ps = 0.f;
#pragma unroll
      for (int e = 0; e < 16; ++e) {
        p[e] = __builtin_amdgcn_exp2f(p[e] - mnew);
        ps += p[e];
      }
      ps += __shfl_xor(ps, 16);
      ps += __shfl_xor(ps, 32);
      L = L * cs + ps;
#pragma unroll
      for (int db = 0; db < 4; ++db) {
        oacc[s][db][0] *= cs; oacc[s][db][1] *= cs;
        oacc[s][db][2] *= cs; oacc[s][db][3] *= cs;
      }
      const bf16x8 pf0 = mkpf(p);
      const bf16x8 pf1 = mkpf(p + 8);
#pragma unroll
      for (int db = 0; db < 4; ++db) {
        oacc[s][db] = __builtin_amdgcn_mfma_f32_16x16x32_bf16(vf[db][0], pf0, oacc[s][db], 0, 0, 0);
        oacc[s][db] = __builtin_amdgcn_mfma_f32_16x16x32_bf16(vf[db][1], pf1, oacc[s][db], 0, 0, 0);
      }
    }

    asm volatile("s_waitcnt vmcnt(0)" ::: "memory");  // next tile arrived
    __builtin_amdgcn_s_barrier();
    asm volatile("" ::: "memory");                    // keep next reads below
  }

  const int b = bh >> 4, h = bh & 15;
#pragma unroll
  for (int s = 0; s < 2; ++s) {
    const float inv = 1.0f / (s ? L1 : L0);
    const int qg = (s ? qsb1 : qsb0) + cx;
    unsigned short* yp = yB + (size_t)(b * 1024 + qg) * 1024 + h * 64;
#pragma unroll
    for (int db = 0; db < 4; ++db) {
      uint2 pv;
      pv.x = (unsigned)f2bf(oacc[s][db][0] * inv) | ((unsigned)f2bf(oacc[s][db][1] * inv) << 16);
      pv.y = (unsigned)f2bf(oacc[s][db][2] * inv) | ((unsigned)f2bf(oacc[s][db][3] * inv) << 16);
      *(uint2*)(yp + db * 16 + (g << 2)) = pv;
    }
  }
}

// ---------------- launch ----------------

extern "C" void kernel_launch(void* const* d_in, const int* in_sizes, int n_in,
                              void* d_out, int out_size, void* d_ws, size_t ws_size,
                              hipStream_t stream) {
  (void)in_sizes; (void)n_in; (void)out_size; (void)ws_size;
  const float* x = (const float*)d_in[0];
  // d_in[1] = attn_mask (static causal tril) — implemented analytically
  const float* w_attn = (const float*)d_in[2];
  const float* b_attn = (const float*)d_in[3];
  const float* w_proj = (const float*)d_in[4];
  const float* b_proj = (const float*)d_in[5];
  float* out = (float*)d_out;

  char* ws = (char*)d_ws;
  unsigned short* xb     = (unsigned short*)(ws);
  unsigned short* wqkvT  = (unsigned short*)(ws + 16777216);
  unsigned short* wprojT = (unsigned short*)(ws + 23068672);
  unsigned short* qb     = (unsigned short*)(ws + 25165824);
  unsigned short* kb     = (unsigned short*)(ws + 41943040);
  unsigned short* vtb    = (unsigned short*)(ws + 58720256);
  unsigned short* yb     = (unsigned short*)(ws + 75497472);

  cvt_x_kernel<<<4096, 256, 0, stream>>>(x, xb);
  cvt_wT_kernel<<<dim3(96, 32), dim3(32, 8), 0, stream>>>(w_attn, wqkvT, 1024, 3072);
  cvt_wT_kernel<<<dim3(32, 32), dim3(32, 8), 0, stream>>>(w_proj, wprojT, 1024, 1024);

  gemm_kernel<0><<<dim3(24, 64), 256, 0, stream>>>(xb, wqkvT, b_attn, nullptr,
                                                   qb, kb, vtb, 8192, 3072, 1024);
  attn_kernel<<<dim3(128, 8), 256, 0, stream>>>(qb, kb, vtb, yb);
  gemm_kernel<1><<<dim3(8, 64), 256, 0, stream>>>(yb, wprojT, b_proj, out,
                                                  nullptr, nullptr, nullptr, 8192, 1024, 1024);
}

// Round 4
// 170.176 us; speedup vs baseline: 2.0225x; 1.0579x over previous
//
#include <hip/hip_runtime.h>

// ---------------------------------------------------------------------------
// CausalSelfAttention: qkv GEMM -> causal flash attention -> proj GEMM
// All matmuls via mfma_f32_16x16x32_bf16 (fp32 accum). bf16 tolerance per harness.
//
// ws layout (bytes):
//   x_bf16   [8192][1024]        @ 0          16,777,216
//   wqkvT    [3072][1024]        @ 16777216    6,291,456
//   wprojT   [1024][1024]        @ 23068672    2,097,152
//   q        [128][1024][64]     @ 25165824   16,777,216   (bh, t, d)  pre-scaled
//   k        [128][1024][64]     @ 41943040   16,777,216
//   vT       [128][64][1024]     @ 58720256   16,777,216   (bh, d, t)
//   y        [8192][1024]        @ 75497472   16,777,216
// total 92,274,688 bytes
// ---------------------------------------------------------------------------

typedef __bf16 bf16x8 __attribute__((ext_vector_type(8)));
typedef float f32x4 __attribute__((ext_vector_type(4)));
typedef unsigned uint4e __attribute__((ext_vector_type(4)));
typedef unsigned short ushort8e __attribute__((ext_vector_type(8)));

typedef __attribute__((address_space(1))) const unsigned as1_u32;
typedef __attribute__((address_space(3))) unsigned as3_u32;

#define NEG_INF (-__builtin_inff())

__device__ __forceinline__ unsigned short f2bf(float f) {
  unsigned u = __builtin_bit_cast(unsigned, f);
  u += 0x7fffu + ((u >> 16) & 1u);   // round-to-nearest-even (finite inputs)
  return (unsigned short)(u >> 16);
}

// ---------------- conversion kernels ----------------

__global__ void cvt_x_kernel(const float* __restrict__ in, unsigned short* __restrict__ out) {
  size_t i = (size_t)(blockIdx.x * 256 + threadIdx.x) * 8;
  float4 a = *(const float4*)(in + i);
  float4 b = *(const float4*)(in + i + 4);
  ushort8e o;
  o[0] = f2bf(a.x); o[1] = f2bf(a.y); o[2] = f2bf(a.z); o[3] = f2bf(a.w);
  o[4] = f2bf(b.x); o[5] = f2bf(b.y); o[6] = f2bf(b.z); o[7] = f2bf(b.w);
  *(ushort8e*)(out + i) = o;
}

// w [K][N] fp32 -> wT [N][K] bf16, 32x32 LDS tile transpose
__global__ void cvt_wT_kernel(const float* __restrict__ w, unsigned short* __restrict__ wT,
                              int K, int N) {
  __shared__ float tile[32][33];
  const int n0 = blockIdx.x * 32, k0 = blockIdx.y * 32;
  const int tx = threadIdx.x, ty = threadIdx.y;
#pragma unroll
  for (int i = 0; i < 32; i += 8)
    tile[ty + i][tx] = w[(size_t)(k0 + ty + i) * N + n0 + tx];
  __syncthreads();
#pragma unroll
  for (int i = 0; i < 32; i += 8)
    wT[(size_t)(n0 + ty + i) * K + k0 + tx] = f2bf(tile[tx][ty + i]);
}

// ---------------- GEMM: C[M,N] = A[M,K](bf16) * BT[N,K](bf16)^T + bias ----------------
// BM=256 x BNT tile, BK=64, 8 waves (2M x 4N), per-wave 128 x BNT/4 output.
// Depth-1 pipeline: stage(t+1) via global_load_lds (16B, linear LDS dest,
// inverse-swizzled global src: chunk ^= row&7) issued BEFORE compute on tile t;
// single vmcnt(0)+barrier AFTER compute. ds_read_b128 applies same XOR.
// EPI 0: scatter to q/k/vT bf16 buffers (qkv GEMM); q pre-scaled by 0.125*log2(e)
// EPI 1: fp32 store to outF (proj GEMM)

template <int EPI, int BNT>
__global__ __launch_bounds__(512, 2) void gemm_kernel(
    const unsigned short* __restrict__ A, const unsigned short* __restrict__ BT,
    const float* __restrict__ bias, float* __restrict__ outF,
    unsigned short* __restrict__ qO, unsigned short* __restrict__ kO,
    unsigned short* __restrict__ vO, int M, int N, int K) {
  constexpr int WN = BNT / 4;        // per-wave cols
  constexpr int NREP = WN / 16;      // 4 (BNT=256) or 2 (BNT=128)
  constexpr int BISS = BNT / 64;     // B staging issues: 4 or 2
  constexpr int ATILE = 256 * 64;    // shorts
  constexpr int BTILE = BNT * 64;
  __shared__ __align__(16) unsigned short LDS[2][ATILE + BTILE];

  const int tid = threadIdx.x;
  const int w = tid >> 6, lane = tid & 63;
  const int g = lane >> 4, cx = lane & 15;
  const int bm = blockIdx.y * 256, bn = blockIdx.x * BNT;
  const int wm = (w >> 2) * 128;     // M-half
  const int wn = (w & 3) * WN;       // N-quarter
  const int NT = K >> 6;

  // staging: issue i covers 64 rows; lane -> row w*8 + (lane>>3), chunk lane&7,
  // global chunk pre-swizzled by row&7 (= (lane>>3)&7). LDS dest wave-linear.
  const int srow = w * 8 + (lane >> 3);
  const int schunk = ((lane & 7) ^ ((lane >> 3) & 7)) << 3;
  const unsigned short* gAr = A + (size_t)(bm + srow) * K + schunk;
  const unsigned short* gBr = BT + (size_t)(bn + srow) * K + schunk;

  auto stage = [&](int t, int buf) {
    const int ko = t * 64;
#pragma unroll
    for (int i = 0; i < 4; ++i)
      __builtin_amdgcn_global_load_lds(
          (as1_u32*)(const void*)(gAr + (size_t)i * 64 * K + ko),
          (as3_u32*)(void*)&LDS[buf][(i * 64 + w * 8) * 64], 16, 0, 0);
#pragma unroll
    for (int i = 0; i < BISS; ++i)
      __builtin_amdgcn_global_load_lds(
          (as1_u32*)(const void*)(gBr + (size_t)i * 64 * K + ko),
          (as3_u32*)(void*)&LDS[buf][ATILE + (i * 64 + w * 8) * 64], 16, 0, 0);
  };

  f32x4 acc[8][NREP] = {};
  const int rsw = cx & 7;  // fragment-read row-swizzle (row&7 == cx&7)

  stage(0, 0);
  asm volatile("s_waitcnt vmcnt(0)" ::: "memory");
  __builtin_amdgcn_s_barrier();
  asm volatile("" ::: "memory");

  for (int t = 0; t < NT; ++t) {
    const int buf = t & 1;
    if (t + 1 < NT) stage(t + 1, buf ^ 1);   // loads in flight across compute
    bf16x8 bfr[NREP][2];
#pragma unroll
    for (int nr = 0; nr < NREP; ++nr) {
      const int RB = wn + nr * 16 + cx;
#pragma unroll
      for (int ks = 0; ks < 2; ++ks)
        bfr[nr][ks] = *(const bf16x8*)&LDS[buf][ATILE + RB * 64 + (((ks * 4 + g) ^ rsw) << 3)];
    }
#pragma unroll
    for (int q = 0; q < 4; ++q) {
      bf16x8 af[2][2];
#pragma unroll
      for (int mr = 0; mr < 2; ++mr) {
        const int R = wm + q * 32 + mr * 16 + cx;
#pragma unroll
        for (int ks = 0; ks < 2; ++ks)
          af[mr][ks] = *(const bf16x8*)&LDS[buf][R * 64 + (((ks * 4 + g) ^ rsw) << 3)];
      }
      __builtin_amdgcn_s_setprio(1);
#pragma unroll
      for (int mr = 0; mr < 2; ++mr)
#pragma unroll
        for (int nr = 0; nr < NREP; ++nr)
#pragma unroll
          for (int ks = 0; ks < 2; ++ks)
            acc[q * 2 + mr][nr] = __builtin_amdgcn_mfma_f32_16x16x32_bf16(
                af[mr][ks], bfr[nr][ks], acc[q * 2 + mr][nr], 0, 0, 0);
      __builtin_amdgcn_s_setprio(0);
    }
    if (t + 1 < NT) {
      asm volatile("s_waitcnt vmcnt(0)" ::: "memory");  // next tile landed
      __builtin_amdgcn_s_barrier();
      asm volatile("" ::: "memory");
    }
  }

  if (EPI == 0) {
#pragma unroll
    for (int q = 0; q < 4; ++q)
#pragma unroll
      for (int mr = 0; mr < 2; ++mr) {
        const int m0 = bm + wm + q * 32 + mr * 16 + (g << 2);
        const int b = m0 >> 10, t0 = m0 & 1023;
#pragma unroll
        for (int nr = 0; nr < NREP; ++nr) {
          const int n = bn + wn + nr * 16 + cx;
          const float bv = bias[n];
          const int which = n >> 10, rem = n & 1023;
          const int h = rem >> 6, d = rem & 63;
          const int bh = b * 16 + h;
          f32x4& a4 = acc[q * 2 + mr][nr];
          if (which == 2) {
            uint2 pv;
            pv.x = (unsigned)f2bf(a4[0] + bv) | ((unsigned)f2bf(a4[1] + bv) << 16);
            pv.y = (unsigned)f2bf(a4[2] + bv) | ((unsigned)f2bf(a4[3] + bv) << 16);
            *(uint2*)(vO + ((size_t)bh * 64 + d) * 1024 + t0) = pv;
          } else {
            unsigned short* dst = (which == 0 ? qO : kO);
            const float scl = (which == 0) ? 0.18033688011112042f : 1.0f;  // 0.125*log2(e)
#pragma unroll
            for (int r = 0; r < 4; ++r)
              dst[((size_t)bh * 1024 + (t0 + r)) * 64 + d] = f2bf((a4[r] + bv) * scl);
          }
        }
      }
  } else {
#pragma unroll
    for (int q = 0; q < 4; ++q)
#pragma unroll
      for (int mr = 0; mr < 2; ++mr) {
        const int m0 = bm + wm + q * 32 + mr * 16 + (g << 2);
#pragma unroll
        for (int nr = 0; nr < NREP; ++nr) {
          const int n = bn + wn + nr * 16 + cx;
          const float bv = bias[n];
          f32x4& a4 = acc[q * 2 + mr][nr];
#pragma unroll
          for (int r = 0; r < 4; ++r)
            outF[(size_t)(m0 + r) * N + n] = a4[r] + bv;
        }
      }
  }
}

// ---------------- causal flash attention (LDS-staged, double-buffered) ----------------
// Block: 4 waves, 128 q rows (wave w owns q-subtiles qb0+w*16 and qb0+64+w*16).
// K/V^T tiles (64 rows x 64 cols bf16) staged via global_load_lds with
// pre-swizzled source (chunk ^= row&7); ds_read_b128 reads apply same XOR.
// S^T = K*Q^T (swapped) -> softmax reduce over lanes {cx, cx+16, cx+32, cx+48};
// P^T rebuilt in-register via shuffles; O^T = V^T * P^T.

__global__ __launch_bounds__(256) void attn_kernel(
    const unsigned short* __restrict__ qB, const unsigned short* __restrict__ kB,
    const unsigned short* __restrict__ vB, unsigned short* __restrict__ yB) {
  __shared__ __align__(16) unsigned short Ks[2][64 * 64];
  __shared__ __align__(16) unsigned short Vs[2][64 * 64];
  const int lane = threadIdx.x & 63, w = threadIdx.x >> 6;
  const int g = lane >> 4, cx = lane & 15;
  const int bh = blockIdx.x;           // head-major: head pinned to XCD bh%8
  const int qt = 7 - blockIdx.y;       // biggest-work q-tiles dispatch first
  const int qb0 = qt * 128;
  const int nt = qt * 2 + 2;           // number of 64-wide k tiles
  const unsigned short* Qh = qB + (size_t)bh * 65536;
  const unsigned short* Kh = kB + (size_t)bh * 65536;
  const unsigned short* Vh = vB + (size_t)bh * 65536;

  const int qsb0 = qb0 + w * 16, qsb1 = qb0 + 64 + w * 16;

  // Q^T B-operand fragments (pre-scaled by 0.125*log2e at qkv epilogue)
  bf16x8 qf[2][2];
#pragma unroll
  for (int s = 0; s < 2; ++s) {
    const int qq = (s ? qsb1 : qsb0) + cx;
#pragma unroll
    for (int h = 0; h < 2; ++h)
      qf[s][h] = *(const bf16x8*)(Qh + (size_t)qq * 64 + h * 32 + g * 8);
  }

  f32x4 oacc[2][4] = {};
  float mrun0 = NEG_INF, mrun1 = NEG_INF, L0 = 0.f, L1 = 0.f;

  const int srl = lane >> 3, sch = lane & 7;  // staging: row-in-8, 16B chunk

  auto stage = [&](int t, int buf) {
#pragma unroll
    for (int i = 0; i < 2; ++i) {
      const int row = w * 16 + i * 8 + srl;
      const int csw = (sch ^ (row & 7)) << 3;
      const unsigned short* gk = Kh + (size_t)(t * 64 + row) * 64 + csw;
      __builtin_amdgcn_global_load_lds((as1_u32*)(const void*)gk,
          (as3_u32*)(void*)&Ks[buf][(w * 16 + i * 8) * 64], 16, 0, 0);
      const unsigned short* gv = Vh + (size_t)row * 1024 + t * 64 + csw;
      __builtin_amdgcn_global_load_lds((as1_u32*)(const void*)gv,
          (as3_u32*)(void*)&Vs[buf][(w * 16 + i * 8) * 64], 16, 0, 0);
    }
  };

  auto mkpf = [&](const float* pp) -> bf16x8 {
    unsigned lo0 = (unsigned)f2bf(pp[0]) | ((unsigned)f2bf(pp[1]) << 16);
    unsigned hi0 = (unsigned)f2bf(pp[2]) | ((unsigned)f2bf(pp[3]) << 16);
    unsigned lo1 = (unsigned)f2bf(pp[4]) | ((unsigned)f2bf(pp[5]) << 16);
    unsigned hi1 = (unsigned)f2bf(pp[6]) | ((unsigned)f2bf(pp[7]) << 16);
    const int s0 = ((g & 1) << 5) + cx, s1 = s0 + 16;
    unsigned a0 = __shfl(lo0, s0), a1 = __shfl(hi0, s0), a2 = __shfl(lo0, s1), a3 = __shfl(hi0, s1);
    unsigned b0 = __shfl(lo1, s0), b1 = __shfl(hi1, s0), b2 = __shfl(lo1, s1), b3 = __shfl(hi1, s1);
    const bool chh = g >= 2;
    uint4e pw;
    pw[0] = chh ? b0 : a0; pw[1] = chh ? b1 : a1; pw[2] = chh ? b2 : a2; pw[3] = chh ? b3 : a3;
    return __builtin_bit_cast(bf16x8, pw);
  };

  stage(0, 0);
  asm volatile("s_waitcnt vmcnt(0)" ::: "memory");
  __builtin_amdgcn_s_barrier();
  asm volatile("" ::: "memory");

  for (int t = 0; t < nt; ++t) {
    const int buf = t & 1;
    if (t + 1 < nt) stage(t + 1, buf ^ 1);   // prefetch overlaps compute
    const int k0 = t * 64;
    const bool act0 = k0 <= qsb0 + 15;       // wave-uniform

    // --- K fragments + QK^T (S^T, base-2 scaled domain) ---
    bf16x8 kf[4][2];
#pragma unroll
    for (int kc = 0; kc < 4; ++kc) {
      const int row = kc * 16 + cx;
#pragma unroll
      for (int h = 0; h < 2; ++h)
        kf[kc][h] = *(const bf16x8*)&Ks[buf][row * 64 + (((h * 4 + g) ^ (row & 7)) << 3)];
    }
    f32x4 sa[2][4];
#pragma unroll
    for (int kc = 0; kc < 4; ++kc) {
      f32x4 z = {0.f, 0.f, 0.f, 0.f};
      sa[1][kc] = __builtin_amdgcn_mfma_f32_16x16x32_bf16(kf[kc][0], qf[1][0], z, 0, 0, 0);
      sa[1][kc] = __builtin_amdgcn_mfma_f32_16x16x32_bf16(kf[kc][1], qf[1][1], sa[1][kc], 0, 0, 0);
    }
    if (act0) {
#pragma unroll
      for (int kc = 0; kc < 4; ++kc) {
        f32x4 z = {0.f, 0.f, 0.f, 0.f};
        sa[0][kc] = __builtin_amdgcn_mfma_f32_16x16x32_bf16(kf[kc][0], qf[0][0], z, 0, 0, 0);
        sa[0][kc] = __builtin_amdgcn_mfma_f32_16x16x32_bf16(kf[kc][1], qf[0][1], sa[0][kc], 0, 0, 0);
      }
    }

    // --- V fragments ---
    bf16x8 vf[4][2];
#pragma unroll
    for (int db = 0; db < 4; ++db) {
      const int row = db * 16 + cx;
#pragma unroll
      for (int h = 0; h < 2; ++h)
        vf[db][h] = *(const bf16x8*)&Vs[buf][row * 64 + (((h * 4 + g) ^ (row & 7)) << 3)];
    }

    // --- softmax + PV per active q-subtile ---
#pragma unroll
    for (int s = 0; s < 2; ++s) {
      if (s == 0 && !act0) continue;
      const int qsb = s ? qsb1 : qsb0;
      const int qg = qsb + cx;
      float& mrun = s ? mrun1 : mrun0;
      float& L = s ? L1 : L0;
      float p[16];
      const bool straddle = (k0 + 63) > qsb;
#pragma unroll
      for (int kc = 0; kc < 4; ++kc)
#pragma unroll
        for (int r = 0; r < 4; ++r) {
          float v = sa[s][kc][r];
          if (straddle && (k0 + kc * 16 + (g << 2) + r) > qg) v = NEG_INF;
          p[kc * 4 + r] = v;
        }
      float m01 = fmaxf(fmaxf(p[0], p[1]), fmaxf(p[2], p[3]));
      float m23 = fmaxf(fmaxf(p[4], p[5]), fmaxf(p[6], p[7]));
      float m45 = fmaxf(fmaxf(p[8], p[9]), fmaxf(p[10], p[11]));
      float m67 = fmaxf(fmaxf(p[12], p[13]), fmaxf(p[14], p[15]));
      float pm = fmaxf(fmaxf(m01, m23), fmaxf(m45, m67));
      pm = fmaxf(pm, __shfl_xor(pm, 16));
      pm = fmaxf(pm, __shfl_xor(pm, 32));
      const float mnew = fmaxf(mrun, pm);
      const float cs = __builtin_amdgcn_exp2f(mrun - mnew);
      mrun = mnew;
      float ps = 0.f;
#pragma unroll
      for (int e = 0; e < 16; ++e) {
        p[e] = __builtin_amdgcn_exp2f(p[e] - mnew);
        ps += p[e];
      }
      ps += __shfl_xor(ps, 16);
      ps += __shfl_xor(ps, 32);
      L = L * cs + ps;
#pragma unroll
      for (int db = 0; db < 4; ++db) {
        oacc[s][db][0] *= cs; oacc[s][db][1] *= cs;
        oacc[s][db][2] *= cs; oacc[s][db][3] *= cs;
      }
      const bf16x8 pf0 = mkpf(p);
      const bf16x8 pf1 = mkpf(p + 8);
#pragma unroll
      for (int db = 0; db < 4; ++db) {
        oacc[s][db] = __builtin_amdgcn_mfma_f32_16x16x32_bf16(vf[db][0], pf0, oacc[s][db], 0, 0, 0);
        oacc[s][db] = __builtin_amdgcn_mfma_f32_16x16x32_bf16(vf[db][1], pf1, oacc[s][db], 0, 0, 0);
      }
    }

    asm volatile("s_waitcnt vmcnt(0)" ::: "memory");  // next tile arrived
    __builtin_amdgcn_s_barrier();
    asm volatile("" ::: "memory");                    // keep next reads below
  }

  const int b = bh >> 4, h = bh & 15;
#pragma unroll
  for (int s = 0; s < 2; ++s) {
    const float inv = 1.0f / (s ? L1 : L0);
    const int qg = (s ? qsb1 : qsb0) + cx;
    unsigned short* yp = yB + (size_t)(b * 1024 + qg) * 1024 + h * 64;
#pragma unroll
    for (int db = 0; db < 4; ++db) {
      uint2 pv;
      pv.x = (unsigned)f2bf(oacc[s][db][0] * inv) | ((unsigned)f2bf(oacc[s][db][1] * inv) << 16);
      pv.y = (unsigned)f2bf(oacc[s][db][2] * inv) | ((unsigned)f2bf(oacc[s][db][3] * inv) << 16);
      *(uint2*)(yp + db * 16 + (g << 2)) = pv;
    }
  }
}

// ---------------- launch ----------------

extern "C" void kernel_launch(void* const* d_in, const int* in_sizes, int n_in,
                              void* d_out, int out_size, void* d_ws, size_t ws_size,
                              hipStream_t stream) {
  (void)in_sizes; (void)n_in; (void)out_size; (void)ws_size;
  const float* x = (const float*)d_in[0];
  // d_in[1] = attn_mask (static causal tril) — implemented analytically
  const float* w_attn = (const float*)d_in[2];
  const float* b_attn = (const float*)d_in[3];
  const float* w_proj = (const float*)d_in[4];
  const float* b_proj = (const float*)d_in[5];
  float* out = (float*)d_out;

  char* ws = (char*)d_ws;
  unsigned short* xb     = (unsigned short*)(ws);
  unsigned short* wqkvT  = (unsigned short*)(ws + 16777216);
  unsigned short* wprojT = (unsigned short*)(ws + 23068672);
  unsigned short* qb     = (unsigned short*)(ws + 25165824);
  unsigned short* kb     = (unsigned short*)(ws + 41943040);
  unsigned short* vtb    = (unsigned short*)(ws + 58720256);
  unsigned short* yb     = (unsigned short*)(ws + 75497472);

  cvt_x_kernel<<<4096, 256, 0, stream>>>(x, xb);
  cvt_wT_kernel<<<dim3(96, 32), dim3(32, 8), 0, stream>>>(w_attn, wqkvT, 1024, 3072);
  cvt_wT_kernel<<<dim3(32, 32), dim3(32, 8), 0, stream>>>(w_proj, wprojT, 1024, 1024);

  gemm_kernel<0, 256><<<dim3(12, 32), 512, 0, stream>>>(xb, wqkvT, b_attn, nullptr,
                                                        qb, kb, vtb, 8192, 3072, 1024);
  attn_kernel<<<dim3(128, 8), 256, 0, stream>>>(qb, kb, vtb, yb);
  gemm_kernel<1, 128><<<dim3(8, 32), 512, 0, stream>>>(yb, wprojT, b_proj, out,
                                                       nullptr, nullptr, nullptr, 8192, 1024, 1024);
}

// Round 5
// 167.407 us; speedup vs baseline: 2.0559x; 1.0165x over previous
//
#include <hip/hip_runtime.h>

// ---------------------------------------------------------------------------
// CausalSelfAttention: qkv GEMM -> causal flash attention -> proj GEMM
// All matmuls via mfma_f32_16x16x32_bf16 (fp32 accum). bf16 tolerance per harness.
//
// ws layout (bytes):
//   x_bf16   [8192][1024]        @ 0          16,777,216
//   wqkvT    [3072][1024]        @ 16777216    6,291,456
//   wprojT   [1024][1024]        @ 23068672    2,097,152
//   q        [128][1024][64]     @ 25165824   16,777,216   (bh, t, d)  pre-scaled
//   k        [128][1024][64]     @ 41943040   16,777,216
//   vT       [128][64][1024]     @ 58720256   16,777,216   (bh, d, t)
//   y        [8192][1024]        @ 75497472   16,777,216
// total 92,274,688 bytes
// ---------------------------------------------------------------------------

typedef __bf16 bf16x8 __attribute__((ext_vector_type(8)));
typedef float f32x4 __attribute__((ext_vector_type(4)));
typedef unsigned uint4e __attribute__((ext_vector_type(4)));
typedef unsigned short ushort8e __attribute__((ext_vector_type(8)));

typedef __attribute__((address_space(1))) const unsigned as1_u32;
typedef __attribute__((address_space(3))) unsigned as3_u32;

#define NEG_INF (-__builtin_inff())

__device__ __forceinline__ unsigned short f2bf(float f) {
  unsigned u = __builtin_bit_cast(unsigned, f);
  u += 0x7fffu + ((u >> 16) & 1u);   // round-to-nearest-even (finite inputs)
  return (unsigned short)(u >> 16);
}

// ---------------- conversion kernels ----------------

__global__ void cvt_x_kernel(const float* __restrict__ in, unsigned short* __restrict__ out) {
  size_t i = (size_t)(blockIdx.x * 256 + threadIdx.x) * 8;
  float4 a = *(const float4*)(in + i);
  float4 b = *(const float4*)(in + i + 4);
  ushort8e o;
  o[0] = f2bf(a.x); o[1] = f2bf(a.y); o[2] = f2bf(a.z); o[3] = f2bf(a.w);
  o[4] = f2bf(b.x); o[5] = f2bf(b.y); o[6] = f2bf(b.z); o[7] = f2bf(b.w);
  *(ushort8e*)(out + i) = o;
}

// w [K][N] fp32 -> wT [N][K] bf16, 32x32 LDS tile transpose
__global__ void cvt_wT_kernel(const float* __restrict__ w, unsigned short* __restrict__ wT,
                              int K, int N) {
  __shared__ float tile[32][33];
  const int n0 = blockIdx.x * 32, k0 = blockIdx.y * 32;
  const int tx = threadIdx.x, ty = threadIdx.y;
#pragma unroll
  for (int i = 0; i < 32; i += 8)
    tile[ty + i][tx] = w[(size_t)(k0 + ty + i) * N + n0 + tx];
  __syncthreads();
#pragma unroll
  for (int i = 0; i < 32; i += 8)
    wT[(size_t)(n0 + ty + i) * K + k0 + tx] = f2bf(tile[tx][ty + i]);
}

// ---------------- GEMM: C[M,N] = A[M,K](bf16) * BT[N,K](bf16)^T + bias ----------------
// BM=256 x BN=128 tile, BK=64, 8 waves (2M x 4N), per-wave 128 x 32 output.
// 3-buffer LDS ring (144 KiB), 2-tiles-ahead prefetch via global_load_lds
// (16B, linear LDS dest, inverse-swizzled global src: chunk ^= row&7).
// Counted s_waitcnt vmcnt(6) per tile (only tile t+1's 6 loads may remain
// outstanding) -- loads stay in flight across barriers (T3/T4).
// Grid flat, bijective XCD swizzle (nwg % 8 == 0 for both call sites).
// EPI 0: scatter to q/k/vT bf16 buffers (qkv GEMM); q pre-scaled by 0.125*log2(e)
// EPI 1: fp32 store to outF (proj GEMM)

template <int EPI, int NTN>
__global__ __launch_bounds__(512, 2) void gemm_kernel(
    const unsigned short* __restrict__ A, const unsigned short* __restrict__ BT,
    const float* __restrict__ bias, float* __restrict__ outF,
    unsigned short* __restrict__ qO, unsigned short* __restrict__ kO,
    unsigned short* __restrict__ vO, int M, int N, int K) {
  constexpr int ATILE = 256 * 64;    // shorts (32 KiB)
  constexpr int BTILE = 128 * 64;    // shorts (16 KiB)
  constexpr int NT = 16;             // K/64 (K=1024 at both call sites)
  __shared__ __align__(16) unsigned short LDS[3][ATILE + BTILE];

  const int tid = threadIdx.x;
  const int w = tid >> 6, lane = tid & 63;
  const int g = lane >> 4, cx = lane & 15;

  // bijective XCD swizzle: grid = NTN*32 blocks, multiple of 8
  constexpr int CPX = NTN * 32 / 8;
  const int bid = blockIdx.x;
  const int wg = (bid & 7) * CPX + (bid >> 3);
  const int bm = (wg / NTN) * 256, bn = (wg % NTN) * 128;

  const int wm = (w >> 2) * 128;     // M-half
  const int wn = (w & 3) * 32;       // N-quarter

  // staging: issue i covers 64 rows; lane -> row w*8 + (lane>>3), chunk lane&7,
  // global chunk pre-swizzled by row&7 (= (lane>>3)&7). LDS dest wave-linear.
  const int srow = w * 8 + (lane >> 3);
  const int schunk = ((lane & 7) ^ ((lane >> 3) & 7)) << 3;
  const unsigned short* gAr = A + (size_t)(bm + srow) * K + schunk;
  const unsigned short* gBr = BT + (size_t)(bn + srow) * K + schunk;

  auto stage = [&](int t) {          // stage tile t into buf t%3
    const int buf = t % 3;
    const int ko = t * 64;
#pragma unroll
    for (int i = 0; i < 4; ++i)
      __builtin_amdgcn_global_load_lds(
          (as1_u32*)(const void*)(gAr + (size_t)i * 64 * K + ko),
          (as3_u32*)(void*)&LDS[buf][(i * 64 + w * 8) * 64], 16, 0, 0);
#pragma unroll
    for (int i = 0; i < 2; ++i)
      __builtin_amdgcn_global_load_lds(
          (as1_u32*)(const void*)(gBr + (size_t)i * 64 * K + ko),
          (as3_u32*)(void*)&LDS[buf][ATILE + (i * 64 + w * 8) * 64], 16, 0, 0);
  };

  f32x4 acc[8][2] = {};
  const int rsw = cx & 7;  // fragment-read row-swizzle (row&7 == cx&7)

  stage(0);
  stage(1);

  for (int t = 0; t < NT; ++t) {
    // tile t's 6 loads were issued 2 tiles ago; only tile t+1's 6 may remain.
    if (t + 1 < NT) asm volatile("s_waitcnt vmcnt(6)" ::: "memory");
    else            asm volatile("s_waitcnt vmcnt(0)" ::: "memory");
    __builtin_amdgcn_s_barrier();            // (a) all waves' tile-t loads landed
    asm volatile("" ::: "memory");
    if (t + 2 < NT) stage(t + 2);            // buf[(t+2)%3] holds dead tile t-1

    const unsigned short* Lb = LDS[t % 3];
    bf16x8 bfr[2][2];
#pragma unroll
    for (int nr = 0; nr < 2; ++nr) {
      const int RB = wn + nr * 16 + cx;
#pragma unroll
      for (int ks = 0; ks < 2; ++ks)
        bfr[nr][ks] = *(const bf16x8*)&Lb[ATILE + RB * 64 + (((ks * 4 + g) ^ rsw) << 3)];
    }
#pragma unroll
    for (int q = 0; q < 4; ++q) {
      bf16x8 af[2][2];
#pragma unroll
      for (int mr = 0; mr < 2; ++mr) {
        const int R = wm + q * 32 + mr * 16 + cx;
#pragma unroll
        for (int ks = 0; ks < 2; ++ks)
          af[mr][ks] = *(const bf16x8*)&Lb[R * 64 + (((ks * 4 + g) ^ rsw) << 3)];
      }
      __builtin_amdgcn_s_setprio(1);
#pragma unroll
      for (int mr = 0; mr < 2; ++mr)
#pragma unroll
        for (int nr = 0; nr < 2; ++nr)
#pragma unroll
          for (int ks = 0; ks < 2; ++ks)
            acc[q * 2 + mr][nr] = __builtin_amdgcn_mfma_f32_16x16x32_bf16(
                af[mr][ks], bfr[nr][ks], acc[q * 2 + mr][nr], 0, 0, 0);
      __builtin_amdgcn_s_setprio(0);
    }
    __builtin_amdgcn_s_barrier();            // (b) reads of buf[t%3] done
    asm volatile("" ::: "memory");
  }

  if (EPI == 0) {
#pragma unroll
    for (int q = 0; q < 4; ++q)
#pragma unroll
      for (int mr = 0; mr < 2; ++mr) {
        const int m0 = bm + wm + q * 32 + mr * 16 + (g << 2);
        const int b = m0 >> 10, t0 = m0 & 1023;
#pragma unroll
        for (int nr = 0; nr < 2; ++nr) {
          const int n = bn + wn + nr * 16 + cx;
          const float bv = bias[n];
          const int which = n >> 10, rem = n & 1023;
          const int h = rem >> 6, d = rem & 63;
          const int bh = b * 16 + h;
          f32x4& a4 = acc[q * 2 + mr][nr];
          if (which == 2) {
            uint2 pv;
            pv.x = (unsigned)f2bf(a4[0] + bv) | ((unsigned)f2bf(a4[1] + bv) << 16);
            pv.y = (unsigned)f2bf(a4[2] + bv) | ((unsigned)f2bf(a4[3] + bv) << 16);
            *(uint2*)(vO + ((size_t)bh * 64 + d) * 1024 + t0) = pv;
          } else {
            unsigned short* dst = (which == 0 ? qO : kO);
            const float scl = (which == 0) ? 0.18033688011112042f : 1.0f;  // 0.125*log2(e)
#pragma unroll
            for (int r = 0; r < 4; ++r)
              dst[((size_t)bh * 1024 + (t0 + r)) * 64 + d] = f2bf((a4[r] + bv) * scl);
          }
        }
      }
  } else {
#pragma unroll
    for (int q = 0; q < 4; ++q)
#pragma unroll
      for (int mr = 0; mr < 2; ++mr) {
        const int m0 = bm + wm + q * 32 + mr * 16 + (g << 2);
#pragma unroll
        for (int nr = 0; nr < 2; ++nr) {
          const int n = bn + wn + nr * 16 + cx;
          const float bv = bias[n];
          f32x4& a4 = acc[q * 2 + mr][nr];
#pragma unroll
          for (int r = 0; r < 4; ++r)
            outF[(size_t)(m0 + r) * N + n] = a4[r] + bv;
        }
      }
  }
}

// ---------------- causal flash attention (LDS-staged, double-buffered) ----------------
// Block: 4 waves, 128 q rows (wave w owns q-subtiles qb0+w*16 and qb0+64+w*16).
// K/V^T tiles (64 rows x 64 cols bf16) staged via global_load_lds with
// pre-swizzled source (chunk ^= row&7); ds_read_b128 reads apply same XOR.
// S^T = K*Q^T (swapped) -> softmax reduce over lanes {cx, cx+16, cx+32, cx+48};
// P^T rebuilt in-register via shuffles; O^T = V^T * P^T.

__global__ __launch_bounds__(256) void attn_kernel(
    const unsigned short* __restrict__ qB, const unsigned short* __restrict__ kB,
    const unsigned short* __restrict__ vB, unsigned short* __restrict__ yB) {
  __shared__ __align__(16) unsigned short Ks[2][64 * 64];
  __shared__ __align__(16) unsigned short Vs[2][64 * 64];
  const int lane = threadIdx.x & 63, w = threadIdx.x >> 6;
  const int g = lane >> 4, cx = lane & 15;
  const int bh = blockIdx.x;           // head-major: head pinned to XCD bh%8
  const int qt = 7 - blockIdx.y;       // biggest-work q-tiles dispatch first
  const int qb0 = qt * 128;
  const int nt = qt * 2 + 2;           // number of 64-wide k tiles
  const unsigned short* Qh = qB + (size_t)bh * 65536;
  const unsigned short* Kh = kB + (size_t)bh * 65536;
  const unsigned short* Vh = vB + (size_t)bh * 65536;

  const int qsb0 = qb0 + w * 16, qsb1 = qb0 + 64 + w * 16;

  // Q^T B-operand fragments (pre-scaled by 0.125*log2e at qkv epilogue)
  bf16x8 qf[2][2];
#pragma unroll
  for (int s = 0; s < 2; ++s) {
    const int qq = (s ? qsb1 : qsb0) + cx;
#pragma unroll
    for (int h = 0; h < 2; ++h)
      qf[s][h] = *(const bf16x8*)(Qh + (size_t)qq * 64 + h * 32 + g * 8);
  }

  f32x4 oacc[2][4] = {};
  float mrun0 = NEG_INF, mrun1 = NEG_INF, L0 = 0.f, L1 = 0.f;

  const int srl = lane >> 3, sch = lane & 7;  // staging: row-in-8, 16B chunk

  auto stage = [&](int t, int buf) {
#pragma unroll
    for (int i = 0; i < 2; ++i) {
      const int row = w * 16 + i * 8 + srl;
      const int csw = (sch ^ (row & 7)) << 3;
      const unsigned short* gk = Kh + (size_t)(t * 64 + row) * 64 + csw;
      __builtin_amdgcn_global_load_lds((as1_u32*)(const void*)gk,
          (as3_u32*)(void*)&Ks[buf][(w * 16 + i * 8) * 64], 16, 0, 0);
      const unsigned short* gv = Vh + (size_t)row * 1024 + t * 64 + csw;
      __builtin_amdgcn_global_load_lds((as1_u32*)(const void*)gv,
          (as3_u32*)(void*)&Vs[buf][(w * 16 + i * 8) * 64], 16, 0, 0);
    }
  };

  auto mkpf = [&](const float* pp) -> bf16x8 {
    unsigned lo0 = (unsigned)f2bf(pp[0]) | ((unsigned)f2bf(pp[1]) << 16);
    unsigned hi0 = (unsigned)f2bf(pp[2]) | ((unsigned)f2bf(pp[3]) << 16);
    unsigned lo1 = (unsigned)f2bf(pp[4]) | ((unsigned)f2bf(pp[5]) << 16);
    unsigned hi1 = (unsigned)f2bf(pp[6]) | ((unsigned)f2bf(pp[7]) << 16);
    const int s0 = ((g & 1) << 5) + cx, s1 = s0 + 16;
    unsigned a0 = __shfl(lo0, s0), a1 = __shfl(hi0, s0), a2 = __shfl(lo0, s1), a3 = __shfl(hi0, s1);
    unsigned b0 = __shfl(lo1, s0), b1 = __shfl(hi1, s0), b2 = __shfl(lo1, s1), b3 = __shfl(hi1, s1);
    const bool chh = g >= 2;
    uint4e pw;
    pw[0] = chh ? b0 : a0; pw[1] = chh ? b1 : a1; pw[2] = chh ? b2 : a2; pw[3] = chh ? b3 : a3;
    return __builtin_bit_cast(bf16x8, pw);
  };

  stage(0, 0);
  asm volatile("s_waitcnt vmcnt(0)" ::: "memory");
  __builtin_amdgcn_s_barrier();
  asm volatile("" ::: "memory");

  for (int t = 0; t < nt; ++t) {
    const int buf = t & 1;
    if (t + 1 < nt) stage(t + 1, buf ^ 1);   // prefetch overlaps compute
    const int k0 = t * 64;
    const bool act0 = k0 <= qsb0 + 15;       // wave-uniform

    // --- K fragments + QK^T (S^T, base-2 scaled domain) ---
    bf16x8 kf[4][2];
#pragma unroll
    for (int kc = 0; kc < 4; ++kc) {
      const int row = kc * 16 + cx;
#pragma unroll
      for (int h = 0; h < 2; ++h)
        kf[kc][h] = *(const bf16x8*)&Ks[buf][row * 64 + (((h * 4 + g) ^ (row & 7)) << 3)];
    }
    f32x4 sa[2][4];
#pragma unroll
    for (int kc = 0; kc < 4; ++kc) {
      f32x4 z = {0.f, 0.f, 0.f, 0.f};
      sa[1][kc] = __builtin_amdgcn_mfma_f32_16x16x32_bf16(kf[kc][0], qf[1][0], z, 0, 0, 0);
      sa[1][kc] = __builtin_amdgcn_mfma_f32_16x16x32_bf16(kf[kc][1], qf[1][1], sa[1][kc], 0, 0, 0);
    }
    if (act0) {
#pragma unroll
      for (int kc = 0; kc < 4; ++kc) {
        f32x4 z = {0.f, 0.f, 0.f, 0.f};
        sa[0][kc] = __builtin_amdgcn_mfma_f32_16x16x32_bf16(kf[kc][0], qf[0][0], z, 0, 0, 0);
        sa[0][kc] = __builtin_amdgcn_mfma_f32_16x16x32_bf16(kf[kc][1], qf[0][1], sa[0][kc], 0, 0, 0);
      }
    }

    // --- V fragments ---
    bf16x8 vf[4][2];
#pragma unroll
    for (int db = 0; db < 4; ++db) {
      const int row = db * 16 + cx;
#pragma unroll
      for (int h = 0; h < 2; ++h)
        vf[db][h] = *(const bf16x8*)&Vs[buf][row * 64 + (((h * 4 + g) ^ (row & 7)) << 3)];
    }

    // --- softmax + PV per active q-subtile ---
#pragma unroll
    for (int s = 0; s < 2; ++s) {
      if (s == 0 && !act0) continue;
      const int qsb = s ? qsb1 : qsb0;
      const int qg = qsb + cx;
      float& mrun = s ? mrun1 : mrun0;
      float& L = s ? L1 : L0;
      float p[16];
      const bool straddle = (k0 + 63) > qsb;
#pragma unroll
      for (int kc = 0; kc < 4; ++kc)
#pragma unroll
        for (int r = 0; r < 4; ++r) {
          float v = sa[s][kc][r];
          if (straddle && (k0 + kc * 16 + (g << 2) + r) > qg) v = NEG_INF;
          p[kc * 4 + r] = v;
        }
      float m01 = fmaxf(fmaxf(p[0], p[1]), fmaxf(p[2], p[3]));
      float m23 = fmaxf(fmaxf(p[4], p[5]), fmaxf(p[6], p[7]));
      float m45 = fmaxf(fmaxf(p[8], p[9]), fmaxf(p[10], p[11]));
      float m67 = fmaxf(fmaxf(p[12], p[13]), fmaxf(p[14], p[15]));
      float pm = fmaxf(fmaxf(m01, m23), fmaxf(m45, m67));
      pm = fmaxf(pm, __shfl_xor(pm, 16));
      pm = fmaxf(pm, __shfl_xor(pm, 32));
      const float mnew = fmaxf(mrun, pm);
      const float cs = __builtin_amdgcn_exp2f(mrun - mnew);
      mrun = mnew;
      float ps = 0.f;
#pragma unroll
      for (int e = 0; e < 16; ++e) {
        p[e] = __builtin_amdgcn_exp2f(p[e] - mnew);
        ps += p[e];
      }
      ps += __shfl_xor(ps, 16);
      ps += __shfl_xor(ps, 32);
      L = L * cs + ps;
#pragma unroll
      for (int db = 0; db < 4; ++db) {
        oacc[s][db][0] *= cs; oacc[s][db][1] *= cs;
        oacc[s][db][2] *= cs; oacc[s][db][3] *= cs;
      }
      const bf16x8 pf0 = mkpf(p);
      const bf16x8 pf1 = mkpf(p + 8);
#pragma unroll
      for (int db = 0; db < 4; ++db) {
        oacc[s][db] = __builtin_amdgcn_mfma_f32_16x16x32_bf16(vf[db][0], pf0, oacc[s][db], 0, 0, 0);
        oacc[s][db] = __builtin_amdgcn_mfma_f32_16x16x32_bf16(vf[db][1], pf1, oacc[s][db], 0, 0, 0);
      }
    }

    asm volatile("s_waitcnt vmcnt(0)" ::: "memory");  // next tile arrived
    __builtin_amdgcn_s_barrier();
    asm volatile("" ::: "memory");                    // keep next reads below
  }

  const int b = bh >> 4, h = bh & 15;
#pragma unroll
  for (int s = 0; s < 2; ++s) {
    const float inv = 1.0f / (s ? L1 : L0);
    const int qg = (s ? qsb1 : qsb0) + cx;
    unsigned short* yp = yB + (size_t)(b * 1024 + qg) * 1024 + h * 64;
#pragma unroll
    for (int db = 0; db < 4; ++db) {
      uint2 pv;
      pv.x = (unsigned)f2bf(oacc[s][db][0] * inv) | ((unsigned)f2bf(oacc[s][db][1] * inv) << 16);
      pv.y = (unsigned)f2bf(oacc[s][db][2] * inv) | ((unsigned)f2bf(oacc[s][db][3] * inv) << 16);
      *(uint2*)(yp + db * 16 + (g << 2)) = pv;
    }
  }
}

// ---------------- launch ----------------

extern "C" void kernel_launch(void* const* d_in, const int* in_sizes, int n_in,
                              void* d_out, int out_size, void* d_ws, size_t ws_size,
                              hipStream_t stream) {
  (void)in_sizes; (void)n_in; (void)out_size; (void)ws_size;
  const float* x = (const float*)d_in[0];
  // d_in[1] = attn_mask (static causal tril) — implemented analytically
  const float* w_attn = (const float*)d_in[2];
  const float* b_attn = (const float*)d_in[3];
  const float* w_proj = (const float*)d_in[4];
  const float* b_proj = (const float*)d_in[5];
  float* out = (float*)d_out;

  char* ws = (char*)d_ws;
  unsigned short* xb     = (unsigned short*)(ws);
  unsigned short* wqkvT  = (unsigned short*)(ws + 16777216);
  unsigned short* wprojT = (unsigned short*)(ws + 23068672);
  unsigned short* qb     = (unsigned short*)(ws + 25165824);
  unsigned short* kb     = (unsigned short*)(ws + 41943040);
  unsigned short* vtb    = (unsigned short*)(ws + 58720256);
  unsigned short* yb     = (unsigned short*)(ws + 75497472);

  cvt_x_kernel<<<4096, 256, 0, stream>>>(x, xb);
  cvt_wT_kernel<<<dim3(96, 32), dim3(32, 8), 0, stream>>>(w_attn, wqkvT, 1024, 3072);
  cvt_wT_kernel<<<dim3(32, 32), dim3(32, 8), 0, stream>>>(w_proj, wprojT, 1024, 1024);

  // QKV: 32 m-tiles x 24 n-tiles = 768 blocks (3 full CU rounds, 768%8==0)
  gemm_kernel<0, 24><<<768, 512, 0, stream>>>(xb, wqkvT, b_attn, nullptr,
                                              qb, kb, vtb, 8192, 3072, 1024);
  attn_kernel<<<dim3(128, 8), 256, 0, stream>>>(qb, kb, vtb, yb);
  // proj: 32 x 8 = 256 blocks (exactly 1 round)
  gemm_kernel<1, 8><<<256, 512, 0, stream>>>(yb, wprojT, b_proj, out,
                                             nullptr, nullptr, nullptr, 8192, 1024, 1024);
}

// Round 6
// 165.900 us; speedup vs baseline: 2.0746x; 1.0091x over previous
//
#include <hip/hip_runtime.h>

// ---------------------------------------------------------------------------
// CausalSelfAttention: qkv GEMM -> causal flash attention -> proj GEMM
// All matmuls via mfma_f32_16x16x32_bf16 (fp32 accum). bf16 tolerance per harness.
//
// ws layout (bytes):
//   x_bf16   [8192][1024]        @ 0          16,777,216
//   wqkvT    [3072][1024]        @ 16777216    6,291,456
//   wprojT   [1024][1024]        @ 23068672    2,097,152
//   q        [128][1024][64]     @ 25165824   16,777,216   (bh, t, d)  pre-scaled
//   k        [128][1024][64]     @ 41943040   16,777,216
//   vT       [128][64][1024]     @ 58720256   16,777,216   (bh, d, t)
//   y        [8192][1024]        @ 75497472   16,777,216
// total 92,274,688 bytes
// ---------------------------------------------------------------------------

typedef __bf16 bf16x8 __attribute__((ext_vector_type(8)));
typedef float f32x4 __attribute__((ext_vector_type(4)));
typedef unsigned uint4e __attribute__((ext_vector_type(4)));
typedef unsigned short ushort8e __attribute__((ext_vector_type(8)));

typedef __attribute__((address_space(1))) const unsigned as1_u32;
typedef __attribute__((address_space(3))) unsigned as3_u32;

#define NEG_INF (-__builtin_inff())

__device__ __forceinline__ unsigned short f2bf(float f) {
  unsigned u = __builtin_bit_cast(unsigned, f);
  u += 0x7fffu + ((u >> 16) & 1u);   // round-to-nearest-even (finite inputs)
  return (unsigned short)(u >> 16);
}

// ---------------- conversion kernels ----------------

__global__ void cvt_x_kernel(const float* __restrict__ in, unsigned short* __restrict__ out) {
  size_t i = (size_t)(blockIdx.x * 256 + threadIdx.x) * 8;
  float4 a = *(const float4*)(in + i);
  float4 b = *(const float4*)(in + i + 4);
  ushort8e o;
  o[0] = f2bf(a.x); o[1] = f2bf(a.y); o[2] = f2bf(a.z); o[3] = f2bf(a.w);
  o[4] = f2bf(b.x); o[5] = f2bf(b.y); o[6] = f2bf(b.z); o[7] = f2bf(b.w);
  *(ushort8e*)(out + i) = o;
}

// w [K][N] fp32 -> wT [N][K] bf16, 32x32 LDS tile transpose
__global__ void cvt_wT_kernel(const float* __restrict__ w, unsigned short* __restrict__ wT,
                              int K, int N) {
  __shared__ float tile[32][33];
  const int n0 = blockIdx.x * 32, k0 = blockIdx.y * 32;
  const int tx = threadIdx.x, ty = threadIdx.y;
#pragma unroll
  for (int i = 0; i < 32; i += 8)
    tile[ty + i][tx] = w[(size_t)(k0 + ty + i) * N + n0 + tx];
  __syncthreads();
#pragma unroll
  for (int i = 0; i < 32; i += 8)
    wT[(size_t)(n0 + ty + i) * K + k0 + tx] = f2bf(tile[tx][ty + i]);
}

// ---------------- GEMM: C[M,N] = A[M,K](bf16) * BT[N,K](bf16)^T + bias ----------------
// 256x256 tile, BK=64, 8 waves (2M x 4N), per-wave 128x64 output (8x4 frags).
// LDS: 2 buffers x (A 256x64 + B 256x64) bf16 = 128 KiB.
// Staging: 8 sub-chunks/tile (64 rows each, 1 global_load_lds per thread),
// issue order B0,B1,B2,B3,A0,A2,A1,A3 one tile ahead, 2 issues per phase.
// 4 phases/tile, each = {issue 2; [wait+barrier on P0/P2]; ds_read; 16 MFMA}.
// Counted waits: P0 vmcnt(2) (only A1,A3(t) may remain), P2 vmcnt(4)
// (only B0-3(t+1) newer than A1,A3(t)) -- uniform across waves since
// P0 consumes A0(wm=0)/A2(wm=128), P2 consumes A1/A3.
// Chunk XOR swizzle (chunk ^= row&7) on global src, same XOR on ds_read.
// EPI 0: scatter to q/k/vT bf16 (qkv); q pre-scaled by 0.125*log2(e)
// EPI 1: fp32 store to outF (proj)

template <int EPI, int NTN>
__global__ __launch_bounds__(512, 2) void gemm_kernel(
    const unsigned short* __restrict__ A, const unsigned short* __restrict__ BT,
    const float* __restrict__ bias, float* __restrict__ outF,
    unsigned short* __restrict__ qO, unsigned short* __restrict__ kO,
    unsigned short* __restrict__ vO, int M, int N, int K) {
  constexpr int NT = 16;               // K/64 (K=1024 at both call sites)
  __shared__ __align__(16) unsigned short LDS[2][32768];  // [A 16384 | B 16384]

  const int tid = threadIdx.x;
  const int w = tid >> 6, lane = tid & 63;
  const int g = lane >> 4, cx = lane & 15;

  // bijective XCD swizzle: grid = NTN*32 blocks, multiple of 8
  constexpr int CPX = NTN * 32 / 8;
  const int bid = blockIdx.x;
  const int wg = (bid & 7) * CPX + (bid >> 3);
  const int bm = (wg / NTN) * 256, bn = (wg % NTN) * 256;

  const int wm = (w >> 2) * 128;       // M-half
  const int wn = (w & 3) * 64;         // N-quarter

  // staging: sub-chunk = 64 rows x 64 cols; thread -> row tid>>3, chunk tid&7,
  // global chunk pre-swizzled by row&7. LDS dest wave-linear (base + lane*16).
  const int srow = tid >> 3;
  const int schunk = ((tid & 7) ^ (srow & 7)) << 3;
  const unsigned short* gA = A + (size_t)(bm + srow) * K + schunk;
  const unsigned short* gB = BT + (size_t)(bn + srow) * K + schunk;
  const int ldst = w * 8 * 64;         // wave's LDS offset within a sub-chunk

  auto issueA = [&](int i, int t) {
    __builtin_amdgcn_global_load_lds(
        (as1_u32*)(const void*)(gA + (size_t)i * 64 * K + t * 64),
        (as3_u32*)(void*)&LDS[t & 1][i * 4096 + ldst], 16, 0, 0);
  };
  auto issueB = [&](int i, int t) {
    __builtin_amdgcn_global_load_lds(
        (as1_u32*)(const void*)(gB + (size_t)i * 64 * K + t * 64),
        (as3_u32*)(void*)&LDS[t & 1][16384 + i * 4096 + ldst], 16, 0, 0);
  };

  f32x4 acc[8][4] = {};
  const int rsw = cx & 7;              // fragment-read swizzle (row&7 == cx&7)

  // prologue: tile 0, order B0..B3, A0, A2, A1, A3
  issueB(0, 0); issueB(1, 0); issueB(2, 0); issueB(3, 0);
  issueA(0, 0); issueA(2, 0); issueA(1, 0); issueA(3, 0);

  for (int t = 0; t < NT; ++t) {
    const unsigned short* Lb = &LDS[t & 1][0];
    // ---------- P0 ----------
    asm volatile("s_waitcnt vmcnt(2)" ::: "memory");   // B*,A0,A2 of t landed
    __builtin_amdgcn_s_barrier();
    asm volatile("" ::: "memory");
    if (t + 1 < NT) { issueB(0, t + 1); issueB(1, t + 1); }
    bf16x8 bfr[4][2];
#pragma unroll
    for (int nf = 0; nf < 4; ++nf) {
      const int RB = wn + nf * 16 + cx;
#pragma unroll
      for (int ks = 0; ks < 2; ++ks)
        bfr[nf][ks] = *(const bf16x8*)&Lb[16384 + RB * 64 + (((ks * 4 + g) ^ rsw) << 3)];
    }
    {
      bf16x8 af[4][2];
#pragma unroll
      for (int mf = 0; mf < 4; ++mf) {
        const int R = wm + mf * 16 + cx;
#pragma unroll
        for (int ks = 0; ks < 2; ++ks)
          af[mf][ks] = *(const bf16x8*)&Lb[R * 64 + (((ks * 4 + g) ^ rsw) << 3)];
      }
      __builtin_amdgcn_s_setprio(1);
#pragma unroll
      for (int mf = 0; mf < 4; ++mf)
#pragma unroll
        for (int nf = 0; nf < 2; ++nf)
#pragma unroll
          for (int ks = 0; ks < 2; ++ks)
            acc[mf][nf] = __builtin_amdgcn_mfma_f32_16x16x32_bf16(
                af[mf][ks], bfr[nf][ks], acc[mf][nf], 0, 0, 0);
      __builtin_amdgcn_s_setprio(0);
      // ---------- P1 ----------
      if (t + 1 < NT) { issueB(2, t + 1); issueB(3, t + 1); }
      __builtin_amdgcn_s_setprio(1);
#pragma unroll
      for (int mf = 0; mf < 4; ++mf)
#pragma unroll
        for (int nf = 2; nf < 4; ++nf)
#pragma unroll
          for (int ks = 0; ks < 2; ++ks)
            acc[mf][nf] = __builtin_amdgcn_mfma_f32_16x16x32_bf16(
                af[mf][ks], bfr[nf][ks], acc[mf][nf], 0, 0, 0);
      __builtin_amdgcn_s_setprio(0);
    }
    // ---------- P2 ----------
    if (t + 1 < NT) asm volatile("s_waitcnt vmcnt(4)" ::: "memory");  // A1,A3 of t landed
    else            asm volatile("s_waitcnt vmcnt(0)" ::: "memory");
    __builtin_amdgcn_s_barrier();
    asm volatile("" ::: "memory");
    if (t + 1 < NT) { issueA(0, t + 1); issueA(2, t + 1); }
    {
      bf16x8 af[4][2];
#pragma unroll
      for (int mf = 0; mf < 4; ++mf) {
        const int R = wm + 64 + mf * 16 + cx;
#pragma unroll
        for (int ks = 0; ks < 2; ++ks)
          af[mf][ks] = *(const bf16x8*)&Lb[R * 64 + (((ks * 4 + g) ^ rsw) << 3)];
      }
      __builtin_amdgcn_s_setprio(1);
#pragma unroll
      for (int mf = 0; mf < 4; ++mf)
#pragma unroll
        for (int nf = 0; nf < 2; ++nf)
#pragma unroll
          for (int ks = 0; ks < 2; ++ks)
            acc[mf + 4][nf] = __builtin_amdgcn_mfma_f32_16x16x32_bf16(
                af[mf][ks], bfr[nf][ks], acc[mf + 4][nf], 0, 0, 0);
      __builtin_amdgcn_s_setprio(0);
      // ---------- P3 ----------
      if (t + 1 < NT) { issueA(1, t + 1); issueA(3, t + 1); }
      __builtin_amdgcn_s_setprio(1);
#pragma unroll
      for (int mf = 0; mf < 4; ++mf)
#pragma unroll
        for (int nf = 2; nf < 4; ++nf)
#pragma unroll
          for (int ks = 0; ks < 2; ++ks)
            acc[mf + 4][nf] = __builtin_amdgcn_mfma_f32_16x16x32_bf16(
                af[mf][ks], bfr[nf][ks], acc[mf + 4][nf], 0, 0, 0);
      __builtin_amdgcn_s_setprio(0);
    }
  }

  if (EPI == 0) {
#pragma unroll
    for (int mf = 0; mf < 8; ++mf) {
      const int m0 = bm + wm + mf * 16 + (g << 2);
      const int b = m0 >> 10, t0 = m0 & 1023;
#pragma unroll
      for (int nf = 0; nf < 4; ++nf) {
        const int n = bn + wn + nf * 16 + cx;
        const float bv = bias[n];
        const int which = n >> 10, rem = n & 1023;
        const int h = rem >> 6, d = rem & 63;
        const int bh = b * 16 + h;
        f32x4& a4 = acc[mf][nf];
        if (which == 2) {
          uint2 pv;
          pv.x = (unsigned)f2bf(a4[0] + bv) | ((unsigned)f2bf(a4[1] + bv) << 16);
          pv.y = (unsigned)f2bf(a4[2] + bv) | ((unsigned)f2bf(a4[3] + bv) << 16);
          *(uint2*)(vO + ((size_t)bh * 64 + d) * 1024 + t0) = pv;
        } else {
          unsigned short* dst = (which == 0 ? qO : kO);
          const float scl = (which == 0) ? 0.18033688011112042f : 1.0f;  // 0.125*log2(e)
#pragma unroll
          for (int r = 0; r < 4; ++r)
            dst[((size_t)bh * 1024 + (t0 + r)) * 64 + d] = f2bf((a4[r] + bv) * scl);
        }
      }
    }
  } else {
#pragma unroll
    for (int mf = 0; mf < 8; ++mf) {
      const int m0 = bm + wm + mf * 16 + (g << 2);
#pragma unroll
      for (int nf = 0; nf < 4; ++nf) {
        const int n = bn + wn + nf * 16 + cx;
        const float bv = bias[n];
        f32x4& a4 = acc[mf][nf];
#pragma unroll
        for (int r = 0; r < 4; ++r)
          outF[(size_t)(m0 + r) * N + n] = a4[r] + bv;
      }
    }
  }
}

// ---------------- causal flash attention (LDS-staged, double-buffered) ----------------
// Block: 4 waves, 128 q rows (wave w owns q-subtiles qb0+w*16 and qb0+64+w*16).
// K/V^T tiles (64 rows x 64 cols bf16) staged via global_load_lds with
// pre-swizzled source (chunk ^= row&7); ds_read_b128 reads apply same XOR.
// S^T = K*Q^T (swapped) -> softmax reduce over lanes {cx, cx+16, cx+32, cx+48};
// P^T rebuilt in-register via shuffles; O^T = V^T * P^T.

__global__ __launch_bounds__(256) void attn_kernel(
    const unsigned short* __restrict__ qB, const unsigned short* __restrict__ kB,
    const unsigned short* __restrict__ vB, unsigned short* __restrict__ yB) {
  __shared__ __align__(16) unsigned short Ks[2][64 * 64];
  __shared__ __align__(16) unsigned short Vs[2][64 * 64];
  const int lane = threadIdx.x & 63, w = threadIdx.x >> 6;
  const int g = lane >> 4, cx = lane & 15;
  const int bh = blockIdx.x;           // head-major: head pinned to XCD bh%8
  const int qt = 7 - blockIdx.y;       // biggest-work q-tiles dispatch first
  const int qb0 = qt * 128;
  const int nt = qt * 2 + 2;           // number of 64-wide k tiles
  const unsigned short* Qh = qB + (size_t)bh * 65536;
  const unsigned short* Kh = kB + (size_t)bh * 65536;
  const unsigned short* Vh = vB + (size_t)bh * 65536;

  const int qsb0 = qb0 + w * 16, qsb1 = qb0 + 64 + w * 16;

  // Q^T B-operand fragments (pre-scaled by 0.125*log2e at qkv epilogue)
  bf16x8 qf[2][2];
#pragma unroll
  for (int s = 0; s < 2; ++s) {
    const int qq = (s ? qsb1 : qsb0) + cx;
#pragma unroll
    for (int h = 0; h < 2; ++h)
      qf[s][h] = *(const bf16x8*)(Qh + (size_t)qq * 64 + h * 32 + g * 8);
  }

  f32x4 oacc[2][4] = {};
  float mrun0 = NEG_INF, mrun1 = NEG_INF, L0 = 0.f, L1 = 0.f;

  const int srl = lane >> 3, sch = lane & 7;  // staging: row-in-8, 16B chunk

  auto stage = [&](int t, int buf) {
#pragma unroll
    for (int i = 0; i < 2; ++i) {
      const int row = w * 16 + i * 8 + srl;
      const int csw = (sch ^ (row & 7)) << 3;
      const unsigned short* gk = Kh + (size_t)(t * 64 + row) * 64 + csw;
      __builtin_amdgcn_global_load_lds((as1_u32*)(const void*)gk,
          (as3_u32*)(void*)&Ks[buf][(w * 16 + i * 8) * 64], 16, 0, 0);
      const unsigned short* gv = Vh + (size_t)row * 1024 + t * 64 + csw;
      __builtin_amdgcn_global_load_lds((as1_u32*)(const void*)gv,
          (as3_u32*)(void*)&Vs[buf][(w * 16 + i * 8) * 64], 16, 0, 0);
    }
  };

  auto mkpf = [&](const float* pp) -> bf16x8 {
    unsigned lo0 = (unsigned)f2bf(pp[0]) | ((unsigned)f2bf(pp[1]) << 16);
    unsigned hi0 = (unsigned)f2bf(pp[2]) | ((unsigned)f2bf(pp[3]) << 16);
    unsigned lo1 = (unsigned)f2bf(pp[4]) | ((unsigned)f2bf(pp[5]) << 16);
    unsigned hi1 = (unsigned)f2bf(pp[6]) | ((unsigned)f2bf(pp[7]) << 16);
    const int s0 = ((g & 1) << 5) + cx, s1 = s0 + 16;
    unsigned a0 = __shfl(lo0, s0), a1 = __shfl(hi0, s0), a2 = __shfl(lo0, s1), a3 = __shfl(hi0, s1);
    unsigned b0 = __shfl(lo1, s0), b1 = __shfl(hi1, s0), b2 = __shfl(lo1, s1), b3 = __shfl(hi1, s1);
    const bool chh = g >= 2;
    uint4e pw;
    pw[0] = chh ? b0 : a0; pw[1] = chh ? b1 : a1; pw[2] = chh ? b2 : a2; pw[3] = chh ? b3 : a3;
    return __builtin_bit_cast(bf16x8, pw);
  };

  stage(0, 0);
  asm volatile("s_waitcnt vmcnt(0)" ::: "memory");
  __builtin_amdgcn_s_barrier();
  asm volatile("" ::: "memory");

  for (int t = 0; t < nt; ++t) {
    const int buf = t & 1;
    if (t + 1 < nt) stage(t + 1, buf ^ 1);   // prefetch overlaps compute
    const int k0 = t * 64;
    const bool act0 = k0 <= qsb0 + 15;       // wave-uniform

    // --- K fragments + QK^T (S^T, base-2 scaled domain) ---
    bf16x8 kf[4][2];
#pragma unroll
    for (int kc = 0; kc < 4; ++kc) {
      const int row = kc * 16 + cx;
#pragma unroll
      for (int h = 0; h < 2; ++h)
        kf[kc][h] = *(const bf16x8*)&Ks[buf][row * 64 + (((h * 4 + g) ^ (row & 7)) << 3)];
    }
    f32x4 sa[2][4];
#pragma unroll
    for (int kc = 0; kc < 4; ++kc) {
      f32x4 z = {0.f, 0.f, 0.f, 0.f};
      sa[1][kc] = __builtin_amdgcn_mfma_f32_16x16x32_bf16(kf[kc][0], qf[1][0], z, 0, 0, 0);
      sa[1][kc] = __builtin_amdgcn_mfma_f32_16x16x32_bf16(kf[kc][1], qf[1][1], sa[1][kc], 0, 0, 0);
    }
    if (act0) {
#pragma unroll
      for (int kc = 0; kc < 4; ++kc) {
        f32x4 z = {0.f, 0.f, 0.f, 0.f};
        sa[0][kc] = __builtin_amdgcn_mfma_f32_16x16x32_bf16(kf[kc][0], qf[0][0], z, 0, 0, 0);
        sa[0][kc] = __builtin_amdgcn_mfma_f32_16x16x32_bf16(kf[kc][1], qf[0][1], sa[0][kc], 0, 0, 0);
      }
    }

    // --- V fragments ---
    bf16x8 vf[4][2];
#pragma unroll
    for (int db = 0; db < 4; ++db) {
      const int row = db * 16 + cx;
#pragma unroll
      for (int h = 0; h < 2; ++h)
        vf[db][h] = *(const bf16x8*)&Vs[buf][row * 64 + (((h * 4 + g) ^ (row & 7)) << 3)];
    }

    // --- softmax + PV per active q-subtile ---
#pragma unroll
    for (int s = 0; s < 2; ++s) {
      if (s == 0 && !act0) continue;
      const int qsb = s ? qsb1 : qsb0;
      const int qg = qsb + cx;
      float& mrun = s ? mrun1 : mrun0;
      float& L = s ? L1 : L0;
      float p[16];
      const bool straddle = (k0 + 63) > qsb;
#pragma unroll
      for (int kc = 0; kc < 4; ++kc)
#pragma unroll
        for (int r = 0; r < 4; ++r) {
          float v = sa[s][kc][r];
          if (straddle && (k0 + kc * 16 + (g << 2) + r) > qg) v = NEG_INF;
          p[kc * 4 + r] = v;
        }
      float m01 = fmaxf(fmaxf(p[0], p[1]), fmaxf(p[2], p[3]));
      float m23 = fmaxf(fmaxf(p[4], p[5]), fmaxf(p[6], p[7]));
      float m45 = fmaxf(fmaxf(p[8], p[9]), fmaxf(p[10], p[11]));
      float m67 = fmaxf(fmaxf(p[12], p[13]), fmaxf(p[14], p[15]));
      float pm = fmaxf(fmaxf(m01, m23), fmaxf(m45, m67));
      pm = fmaxf(pm, __shfl_xor(pm, 16));
      pm = fmaxf(pm, __shfl_xor(pm, 32));
      const float mnew = fmaxf(mrun, pm);
      const float cs = __builtin_amdgcn_exp2f(mrun - mnew);
      mrun = mnew;
      float ps = 0.f;
#pragma unroll
      for (int e = 0; e < 16; ++e) {
        p[e] = __builtin_amdgcn_exp2f(p[e] - mnew);
        ps += p[e];
      }
      ps += __shfl_xor(ps, 16);
      ps += __shfl_xor(ps, 32);
      L = L * cs + ps;
#pragma unroll
      for (int db = 0; db < 4; ++db) {
        oacc[s][db][0] *= cs; oacc[s][db][1] *= cs;
        oacc[s][db][2] *= cs; oacc[s][db][3] *= cs;
      }
      const bf16x8 pf0 = mkpf(p);
      const bf16x8 pf1 = mkpf(p + 8);
#pragma unroll
      for (int db = 0; db < 4; ++db) {
        oacc[s][db] = __builtin_amdgcn_mfma_f32_16x16x32_bf16(vf[db][0], pf0, oacc[s][db], 0, 0, 0);
        oacc[s][db] = __builtin_amdgcn_mfma_f32_16x16x32_bf16(vf[db][1], pf1, oacc[s][db], 0, 0, 0);
      }
    }

    asm volatile("s_waitcnt vmcnt(0)" ::: "memory");  // next tile arrived
    __builtin_amdgcn_s_barrier();
    asm volatile("" ::: "memory");                    // keep next reads below
  }

  const int b = bh >> 4, h = bh & 15;
#pragma unroll
  for (int s = 0; s < 2; ++s) {
    const float inv = 1.0f / (s ? L1 : L0);
    const int qg = (s ? qsb1 : qsb0) + cx;
    unsigned short* yp = yB + (size_t)(b * 1024 + qg) * 1024 + h * 64;
#pragma unroll
    for (int db = 0; db < 4; ++db) {
      uint2 pv;
      pv.x = (unsigned)f2bf(oacc[s][db][0] * inv) | ((unsigned)f2bf(oacc[s][db][1] * inv) << 16);
      pv.y = (unsigned)f2bf(oacc[s][db][2] * inv) | ((unsigned)f2bf(oacc[s][db][3] * inv) << 16);
      *(uint2*)(yp + db * 16 + (g << 2)) = pv;
    }
  }
}

// ---------------- launch ----------------

extern "C" void kernel_launch(void* const* d_in, const int* in_sizes, int n_in,
                              void* d_out, int out_size, void* d_ws, size_t ws_size,
                              hipStream_t stream) {
  (void)in_sizes; (void)n_in; (void)out_size; (void)ws_size;
  const float* x = (const float*)d_in[0];
  // d_in[1] = attn_mask (static causal tril) — implemented analytically
  const float* w_attn = (const float*)d_in[2];
  const float* b_attn = (const float*)d_in[3];
  const float* w_proj = (const float*)d_in[4];
  const float* b_proj = (const float*)d_in[5];
  float* out = (float*)d_out;

  char* ws = (char*)d_ws;
  unsigned short* xb     = (unsigned short*)(ws);
  unsigned short* wqkvT  = (unsigned short*)(ws + 16777216);
  unsigned short* wprojT = (unsigned short*)(ws + 23068672);
  unsigned short* qb     = (unsigned short*)(ws + 25165824);
  unsigned short* kb     = (unsigned short*)(ws + 41943040);
  unsigned short* vtb    = (unsigned short*)(ws + 58720256);
  unsigned short* yb     = (unsigned short*)(ws + 75497472);

  cvt_x_kernel<<<4096, 256, 0, stream>>>(x, xb);
  cvt_wT_kernel<<<dim3(96, 32), dim3(32, 8), 0, stream>>>(w_attn, wqkvT, 1024, 3072);
  cvt_wT_kernel<<<dim3(32, 32), dim3(32, 8), 0, stream>>>(w_proj, wprojT, 1024, 1024);

  // QKV: 32 m-tiles x 12 n-tiles = 384 blocks (384%8==0)
  gemm_kernel<0, 12><<<384, 512, 0, stream>>>(xb, wqkvT, b_attn, nullptr,
                                              qb, kb, vtb, 8192, 3072, 1024);
  attn_kernel<<<dim3(128, 8), 256, 0, stream>>>(qb, kb, vtb, yb);
  // proj: 32 x 4 = 128 blocks (128%8==0)
  gemm_kernel<1, 4><<<128, 512, 0, stream>>>(yb, wprojT, b_proj, out,
                                             nullptr, nullptr, nullptr, 8192, 1024, 1024);
}